// Round 7
// baseline (196126.501 us; speedup 1.0000x reference)
//
#include <hip/hip_runtime.h>
#include <math.h>

// ---------------------------------------------------------------------------
// Persistent-kernel trainer for the 16384-step sequential MLP scan.
// R16: latency-hiding micro-round on the harness-verified R15 skeleton
// (192.5k us; NWG=256, CW=4, NBANK=8, AC padded 128B, 2 syncs/step).
// FETCH_SIZE (~234KB/step) shows atomic-hot + streamed lines are HBM-latency
// touches; several were issued serially at point of use. Changes:
//  1) tgt[t], NX[t-1], SD[t] hoisted to Phase-A top (hide ~0.7us under
//     AC/O1R reads + wredf chains; OOB-guarded at t==NSTEP)
//  2) x-row register pipeline: xp(t) == xn(t-2) -> 2 rotating VGPRs,
//     shadow does 1 global row load instead of 2
//  3) P3 banks 16 -> 8 (halve P3 hot lines; R12-direction)
//  4) m2/a2sq AC adds moved tid0 -> tid64 (wave1): wave0's P-arrive drain
//     waits only the P3 ack (the only P-gated publish).
// No sync-protocol changes (structural edits failed 3/3 in harness).
// ---------------------------------------------------------------------------

#define NSTEP 16384
#define INDIM 1024
#define HID   1024
#define OUTD  64
#define LR    0.01f
#define EPSN  1e-8f

#define NWG   256
#define TPB   1024
#define CW    4
#define NBANK 8      // O1R banks
#define P3B   8      // P3 banks (was 16)
#define CSTR  32     // counter stride in ints (128 B)

// workspace layout (float/int indices)
#define OFF_ARRIVE   0                         // 256 ints (init barrier)
#define OFF_RELEASE  512                       // 1 int
#define OFF_PCNT     1024                      // 16 counters, stride 32 ints
#define OFF_QCNT     2048                      // 16 counters, stride 32 ints
#define OFF_U        4096                      // HID floats
#define OFF_O1R      (OFF_U + HID)             // 2*NBANK*HID
#define OFF_P3       (OFF_O1R + 2*NBANK*HID)   // 2*P3B*OUTD
#define OFF_ACC      (OFF_P3 + 2*P3B*OUTD)     // 2*16*32 (banks padded to 128B)
#define OFF_SDOT     (OFF_ACC + 2*16*32)       // NSTEP
#define OFF_NORMX    (OFF_SDOT + NSTEP)        // NSTEP

// ACC slots: 0 m1, 1 m2, 2 m3, 3 dot_d2o2, 4 sum_o2sq, 5 sum_B2sq, 6 sum_a2sq

__device__ __forceinline__ float dload(const float* p){
  return __hip_atomic_load(p, __ATOMIC_RELAXED, __HIP_MEMORY_SCOPE_AGENT);
}
__device__ __forceinline__ void dstore(float* p, float v){
  __hip_atomic_store(p, v, __ATOMIC_RELAXED, __HIP_MEMORY_SCOPE_AGENT);
}
__device__ __forceinline__ int rload(const int* p){
  return __hip_atomic_load(p, __ATOMIC_RELAXED, __HIP_MEMORY_SCOPE_AGENT);
}
__device__ __forceinline__ void rstore(int* p, int v){
  __hip_atomic_store(p, v, __ATOMIC_RELAXED, __HIP_MEMORY_SCOPE_AGENT);
}
__device__ __forceinline__ void iadd(int* p){
  __hip_atomic_fetch_add(p, 1, __ATOMIC_RELAXED, __HIP_MEMORY_SCOPE_AGENT);
}
__device__ __forceinline__ float wredf(float v){
  #pragma unroll
  for (int m = 32; m; m >>= 1) v += __shfl_xor(v, m, 64);
  return v;
}
__device__ __forceinline__ float sigf(float z){ return 1.f/(1.f+__expf(-z)); }

__global__ __launch_bounds__(64) void bp_init(const float* __restrict__ x, float* wsf){
  const int t = blockIdx.x, tid = threadIdx.x;
  const float* xt = x + (size_t)t * INDIM;
  const float* xp = x + (size_t)(t > 0 ? t - 1 : 0) * INDIM;
  float sp = 0.f, nx = 0.f;
  #pragma unroll
  for (int e = 0; e < INDIM/64; e++){
    int i = tid + 64*e; float a = xt[i];
    nx += a*a; sp += a*xp[i];
  }
  sp = wredf(sp); nx = wredf(nx);
  if (tid == 0){ wsf[OFF_SDOT + t] = (t > 0) ? sp : 0.f; wsf[OFF_NORMX + t] = nx; }
  if (blockIdx.x == 0){
    int* wsi = (int*)wsf;
    for (int i = tid; i < 256; i += 64) wsi[OFF_ARRIVE + i] = 0;
    if (tid == 0) wsi[OFF_RELEASE] = 0;
    if (tid < 16){ wsi[OFF_PCNT + CSTR*tid] = 0; wsi[OFF_QCNT + CSTR*tid] = 0; }
    for (int i = tid; i < 2*NBANK*HID; i += 64) wsf[OFF_O1R + i] = 0.f;
    for (int i = tid; i < 2*P3B*OUTD;  i += 64) wsf[OFF_P3 + i]  = 0.f;
    for (int i = tid; i < 2*16*32;     i += 64) wsf[OFF_ACC + i] = 0.f;
    __syncthreads();
    if (tid == 0){
      float* acc1 = wsf + OFF_ACC + 16*32;   // parity-1, bank-0
      acc1[0] = 1.f; acc1[1] = 1.f; acc1[2] = 1.f; acc1[5] = 1.f;
    }
  }
}

__global__ __launch_bounds__(TPB) void bp_train(
    const float* __restrict__ xdat, const float* __restrict__ tgt,
    const float* __restrict__ w1g, const float* __restrict__ b1g,
    const float* __restrict__ w2g, const float* __restrict__ b2g,
    const float* __restrict__ w3g, const float* __restrict__ b3g,
    float* __restrict__ out, float* wsf)
{
  alignas(16) __shared__ float s1r[HID*CW];   // w1 ROW-major: [i][j]
  alignas(16) __shared__ float s2[CW*HID];    // w2 col-major: [j][i]
  __shared__ float s3[CW*OUTD];               // w3 rows
  alignas(16) __shared__ float a1b[2][HID];
  __shared__ float d1s[HID];
  __shared__ float b1s[HID];
  __shared__ float o1f[HID];
  __shared__ float d3b[2][OUTD];
  __shared__ float p3r[OUTD];
  __shared__ float b3s[OUTD];
  __shared__ float o2l[CW], d2l[CW], b2l[CW];
  __shared__ float a2b[2][CW];
  __shared__ float ascr[256];

  const int tid = threadIdx.x;
  const int wg  = blockIdx.x;
  int*   arrive  = (int*)wsf + OFF_ARRIVE;
  int*   release = (int*)wsf + OFF_RELEASE;
  int*   PCNT    = (int*)wsf + OFF_PCNT;
  int*   QCNT    = (int*)wsf + OFF_QCNT;
  float* U   = wsf + OFF_U;
  float* O1R = wsf + OFF_O1R;
  float* P3  = wsf + OFF_P3;
  float* AC  = wsf + OFF_ACC;
  float* SD  = wsf + OFF_SDOT;
  float* NX  = wsf + OFF_NORMX;
  const int bank  = wg & 15;
  const int obank = wg & (NBANK-1);
  const int bank3 = wg & (P3B-1);
  const int wid   = tid >> 6;

  // ---- load owned slices + replicas, zero state ----
  {
    const float4 wv = *reinterpret_cast<const float4*>(&w1g[(size_t)tid*HID + wg*CW]);
    *reinterpret_cast<float4*>(&s1r[4*tid]) = wv;
  }
  for (int v = tid; v < CW*HID; v += TPB){
    int j = v & (CW-1); int i = v >> 2;
    s2[j*HID + i] = w2g[(size_t)i*HID + wg*CW + j];
  }
  if (tid < CW*OUTD){
    int i = tid >> 6; int k = tid & 63;
    s3[tid] = w3g[(size_t)(wg*CW + i)*OUTD + k];
  }
  b1s[tid] = b1g[tid]; d1s[tid] = 0.f; o1f[tid] = 0.f; a1b[1][tid] = 0.f;
  if (tid < OUTD){ b3s[tid] = b3g[tid]; d3b[1][tid] = 0.f; p3r[tid] = 0.f; }
  if (tid < CW){
    b2l[tid] = b2g[wg*CW + tid];
    o2l[tid] = 0.f; d2l[tid] = 0.f; a2b[0][tid] = 0.f; a2b[1][tid] = 0.f;
  }
  __syncthreads();

  // x-row register pipeline: xr{0,1} hold rows of x; both start at row 0
  float xr0, xr1;

  // ---- publish u for step 0 ----
  {
    float xv = xdat[tid];
    xr0 = xv; xr1 = xv;                 // row 0 into both slots
    float4 w = *reinterpret_cast<const float4*>(&s1r[4*tid]);
    float u0_ = wredf(xv*w.x), u1_ = wredf(xv*w.y);
    float u2_ = wredf(xv*w.z), u3_ = wredf(xv*w.w);
    if ((tid & 63) == 0){
      ascr[wid*4+0]=u0_; ascr[wid*4+1]=u1_; ascr[wid*4+2]=u2_; ascr[wid*4+3]=u3_;
    }
    __syncthreads();
    if (tid < CW){
      float s = 0.f;
      for (int w2_ = 0; w2_ < 16; w2_++) s += ascr[w2_*4 + tid];
      dstore(&U[wg*CW + tid], s);
    }
  }
  // initial full funnel barrier (once)
  {
    asm volatile("s_waitcnt vmcnt(0) lgkmcnt(0)" ::: "memory");
    __syncthreads();
    if (tid == 0) rstore(&arrive[wg], 1);
    if (wg == 0){
      if (tid < NWG){ while (rload(&arrive[tid]) < 1) __builtin_amdgcn_s_sleep(1); }
      __syncthreads();
      if (tid == 0) rstore(release, 1);
    }
    if (tid == 0){ while (rload(release) < 1) __builtin_amdgcn_s_sleep(1); }
    __syncthreads();
    asm volatile("" ::: "memory");
  }

  for (int t = 0; t <= NSTEP; t++){
    const int p = t & 1, qq = p ^ 1;
    float* a1c = a1b[p];  float* a1p = a1b[qq];
    float* a2c = a2b[p];  float* a2p = a2b[qq];
    float* d3c = d3b[p];  float* d3p = d3b[qq];

    // ================= Phase A =================
    // hoisted cold loads: issued early, consumed ~1-5us later
    float nxp = NX[t > 0 ? t - 1 : 0];
    float sdt = SD[t < NSTEP ? t : 0];
    float tv_pf = (t < NSTEP && tid < OUTD) ? tgt[(size_t)t*OUTD + tid] : 0.f;

    if (tid < 112){
      int s = tid >> 4, b = tid & 15;
      ascr[128 + s*16 + b] = dload(&AC[(qq*16 + b)*32 + s]);
    }
    float u0 = dload(&U[tid]);
    float r0 = 0.f;
    #pragma unroll
    for (int b = 0; b < NBANK; b++)
      r0 += dload(&O1R[(qq*NBANK + b)*HID + tid]);
    float a1p0 = a1p[tid];
    float of0 = r0 * a1p0 * (1.f - a1p0);
    o1f[tid] = of0;

    // stage 2: per-wave partials
    {
      float v0 = d1s[tid]*of0;
      float v1 = of0*of0;
      float Ba = b1s[tid] - LR*of0;
      float v2 = Ba*Ba;
      float v3 = a1p0*a1p0;
      v0 = wredf(v0); v1 = wredf(v1); v2 = wredf(v2); v3 = wredf(v3);
      if ((tid & 63) == 0){
        ascr[0*16+wid]=v0; ascr[1*16+wid]=v1; ascr[2*16+wid]=v2; ascr[3*16+wid]=v3;
      }
      if (tid < 64){
        float d3v = d3p[tid];
        float v4 = d3v*d3v;
        float B3 = b3s[tid] - LR*d3v; float v5 = B3*B3;
        float v6 = d3v * p3r[tid];
        v4 = wredf(v4); v5 = wredf(v5); v6 = wredf(v6);
        if (tid == 0){ ascr[244]=v4; ascr[245]=v5; ascr[246]=v6; }
      }
    }
    __syncthreads();
    if (tid < 64){
      if (tid < 4){
        float s = 0.f;
        #pragma unroll
        for (int w = 0; w < 16; w++) s += ascr[tid*16 + w];
        ascr[240 + tid] = s;
      } else if (tid >= 8 && tid < 15){
        int s_ = tid - 8;
        float s = 0.f;
        #pragma unroll
        for (int b = 0; b < 16; b++) s += ascr[128 + s_*16 + b];
        ascr[248 + s_] = s;
      }
    }
    __syncthreads();
    float dd  = ascr[240], so  = ascr[241], sb  = ascr[242], sa1 = ascr[243];
    float sd3 = ascr[244], sb3 = ascr[245], dp3 = ascr[246];
    float m1p = ascr[248], m2p = ascr[249], m3p = ascr[250], dq  = ascr[251];
    float soq = ascr[252], sB2 = ascr[253], sa2 = ascr[254];

    float n1  = fmaxf(sqrtf(fmaxf(m1p - 2.f*LR*dd  + LR*LR*nxp*so,  0.f)), EPSN);
    float nb1 = fmaxf(sqrtf(sb),  EPSN);
    float n2  = fmaxf(sqrtf(fmaxf(m2p - 2.f*LR*dq  + LR*LR*sa1*soq, 0.f)), EPSN);
    float nb2 = fmaxf(sqrtf(sB2), EPSN);
    float n3  = fmaxf(sqrtf(fmaxf(m3p - 2.f*LR*dp3 + LR*LR*sa2*sd3, 0.f)), EPSN);
    float nb3 = fmaxf(sqrtf(sb3), EPSN);
    float rn1 = 1.f/n1, rnb1 = 1.f/nb1, rn2 = 1.f/n2, rnb2 = 1.f/nb2;
    float rn3 = 1.f/n3, rnb3 = 1.f/nb3;

    // stage 3
    {
      float B0 = (b1s[tid] - LR*of0)*rnb1; b1s[tid] = B0;
      float dn0 = (u0 - LR*of0*sdt)*rn1;   d1s[tid] = dn0;
      a1c[tid] = sigf(dn0 + B0);
    }
    __syncthreads();

    // stage 4: fused W2 update + matvec
    {
      int j = tid >> 8, l = tid & 255;
      float coef = LR * o2l[j];
      float4 w  = *reinterpret_cast<float4*>(&s2[j*HID + 4*l]);
      float4 ap = *reinterpret_cast<const float4*>(&a1p[4*l]);
      float4 ac = *reinterpret_cast<const float4*>(&a1c[4*l]);
      w.x = (w.x - coef*ap.x)*rn2;  w.y = (w.y - coef*ap.y)*rn2;
      w.z = (w.z - coef*ap.z)*rn2;  w.w = (w.w - coef*ap.w)*rn2;
      *reinterpret_cast<float4*>(&s2[j*HID + 4*l]) = w;
      float acc = ac.x*w.x + ac.y*w.y + ac.z*w.z + ac.w*w.w;
      float ms  = w.x*w.x + w.y*w.y + w.z*w.z + w.w*w.w;
      acc = wredf(acc); ms = wredf(ms);
      if ((tid & 63) == 0){ ascr[wid] = acc; ascr[16 + wid] = ms; }
    }
    __syncthreads();
    if (tid < CW){
      float d2 = ascr[4*tid] + ascr[4*tid+1] + ascr[4*tid+2] + ascr[4*tid+3];
      d2l[tid] = d2;
      float b2n = (b2l[tid] - LR*o2l[tid])*rnb2;
      b2l[tid] = b2n;
      a2c[tid] = sigf(d2 + b2n);
    }
    __syncthreads();
    // moved off wave0 (tid0 -> tid64): keeps wave0's P-arrive drain P3-only;
    // these AC slots are Q-gated (consumed next step), ack drains at Q-arrive
    if (tid == 64){
      float m2 = 0.f;
      #pragma unroll
      for (int w = 0; w < 16; w++) m2 += ascr[16 + w];
      unsafeAtomicAdd(&AC[(p*16 + bank)*32 + 1], m2);
      float s = 0.f;
      for (int j = 0; j < CW; j++){ float a = a2c[j]; s += a*a; }
      unsafeAtomicAdd(&AC[(p*16 + bank)*32 + 6], s);
    }

    // stage 5: fused W3 update + P3 publish (wave0 only)
    if (tid < OUTD){
      int k = tid;
      float d3k = d3p[k];
      float contrib = 0.f, m3s = 0.f;
      #pragma unroll
      for (int i = 0; i < CW; i++){
        float w = s3[i*OUTD + k];
        w = (w - LR*a2p[i]*d3k)*rn3;
        s3[i*OUTD + k] = w;
        contrib += a2c[i]*w;
        m3s += w*w;
      }
      unsafeAtomicAdd(&P3[(p*P3B + bank3)*OUTD + k], contrib);
      m3s = wredf(m3s);
      if (k == 0) unsafeAtomicAdd(&AC[(p*16 + bank)*32 + 2], m3s);
      b3s[k] = (b3s[k] - LR*d3k)*rnb3;
    }

    // ===== epilogue =====
    if (t == NSTEP){
      __syncthreads();
      const float* xl = xdat + (size_t)(NSTEP - 1)*INDIM;
      float xv = xl[tid];
      float c0 = LR*o1f[wg*CW+0], c1 = LR*o1f[wg*CW+1];
      float c2 = LR*o1f[wg*CW+2], c3 = LR*o1f[wg*CW+3];
      float4 w = *reinterpret_cast<const float4*>(&s1r[4*tid]);
      float4 ov;
      ov.x = (w.x - c0*xv)*rn1; ov.y = (w.y - c1*xv)*rn1;
      ov.z = (w.z - c2*xv)*rn1; ov.w = (w.w - c3*xv)*rn1;
      *reinterpret_cast<float4*>(&out[(size_t)tid*HID + wg*CW]) = ov;
      float4 o2v;
      o2v.x = s2[0*HID+tid]; o2v.y = s2[1*HID+tid];
      o2v.z = s2[2*HID+tid]; o2v.w = s2[3*HID+tid];
      *reinterpret_cast<float4*>(&out[(size_t)HID*HID + (size_t)tid*HID + wg*CW]) = o2v;
      if (tid < OUTD){
        #pragma unroll
        for (int i = 0; i < CW; i++)
          out[(size_t)2*HID*HID + (size_t)(wg*CW + i)*OUTD + tid] = s3[i*OUTD + tid];
      }
      break;
    }

    // ---- P-arrive: all P-side publishes are wave0's atomics ----
    if (wid == 0){
      asm volatile("s_waitcnt vmcnt(0) lgkmcnt(0)" ::: "memory");
      if (tid == 0) iadd(&PCNT[CSTR*bank]);
    }

    // ---- shadow (WG-local): fused W1 update + u_{t+1} partials + m1 ----
    float u_pub = 0.f;
    {
      const float* xn_ = xdat + (size_t)(t + 1 < NSTEP ? t + 1 : NSTEP - 1)*INDIM;
      float xpv = (t & 1) ? xr0 : xr1;   // row t-1, loaded 2 steps ago (row 0 at t<2)
      float xnv = xn_[tid];
      if (t & 1) xr0 = xnv; else xr1 = xnv;
      float c0 = LR*o1f[wg*CW+0], c1 = LR*o1f[wg*CW+1];
      float c2 = LR*o1f[wg*CW+2], c3 = LR*o1f[wg*CW+3];
      float4 w = *reinterpret_cast<float4*>(&s1r[4*tid]);
      w.x = (w.x - c0*xpv)*rn1; w.y = (w.y - c1*xpv)*rn1;
      w.z = (w.z - c2*xpv)*rn1; w.w = (w.w - c3*xpv)*rn1;
      *reinterpret_cast<float4*>(&s1r[4*tid]) = w;
      float m1s = w.x*w.x + w.y*w.y + w.z*w.z + w.w*w.w;
      float u0_ = wredf(xnv*w.x), u1_ = wredf(xnv*w.y);
      float u2_ = wredf(xnv*w.z), u3_ = wredf(xnv*w.w);
      m1s = wredf(m1s);
      if ((tid & 63) == 0){
        ascr[wid*4+0]=u0_; ascr[wid*4+1]=u1_; ascr[wid*4+2]=u2_; ascr[wid*4+3]=u3_;
        ascr[64 + wid] = m1s;
      }
      __syncthreads();
      if (tid < CW){
        float s = 0.f;
        #pragma unroll
        for (int w2_ = 0; w2_ < 16; w2_++) s += ascr[w2_*4 + tid];
        u_pub = s;
      }
      if (tid == 0){
        float m1 = 0.f;
        #pragma unroll
        for (int w2_ = 0; w2_ < 16; w2_++) m1 += ascr[64 + w2_];
        unsafeAtomicAdd(&AC[(p*16 + bank)*32 + 0], m1);
      }
    }

    // ---- P-wait: poll 16 padded producer counters (one line each) ----
    {
      const int ptgt = 16*(t+1);
      if (tid < 16){
        while (rload(&PCNT[CSTR*tid]) < ptgt) __builtin_amdgcn_s_sleep(1);
      }
      __syncthreads();
      asm volatile("" ::: "memory");
    }

    // ================= Phase B =================
    // early zeroing of next-parity accumulators (safe: P-wait proves all WGs
    // consumed their Phase-A qq reads); acks overlap Phase B compute
    if (wg < NBANK) dstore(&O1R[(qq*NBANK + wg)*HID + tid], 0.f);
    if (wg < P3B && tid < OUTD) dstore(&P3[(qq*P3B + wg)*OUTD + tid], 0.f);
    if (wg < 16  && tid < 8)    dstore(&AC[(qq*16 + wg)*32 + tid], 0.f);
    if (tid < CW) dstore(&U[wg*CW + tid], u_pub);   // safe: all WGs past A stage1
    // prefetch s2 row (stable since stage 4) for the o1 partial
    float s2v0 = s2[0*HID+tid], s2v1 = s2[1*HID+tid];
    float s2v2 = s2[2*HID+tid], s2v3 = s2[3*HID+tid];

    if (tid < OUTD){
      float s = 0.f;
      #pragma unroll
      for (int b = 0; b < P3B; b++) s += dload(&P3[(p*P3B + b)*OUTD + tid]);
      p3r[tid] = s;
      float a3 = sigf(s + b3s[tid]);
      float e3 = __expf(-a3);
      float es = wredf(e3);
      float net = e3 / es;
      d3c[tid] = (tv_pf - net) * a3 * (1.f - a3);
    }
    __syncthreads();
    if (tid < CW*OUTD){
      int i = tid >> 6, k = tid & 63;
      float v = wredf(s3[i*OUTD + k] * d3c[k]);
      if (k == 0){ float a2v = a2c[i]; o2l[i] = v * a2v * (1.f - a2v); }
    }
    __syncthreads();
    if (tid == 0){
      float dd2 = 0.f, so2 = 0.f, sB2n = 0.f;
      for (int j = 0; j < CW; j++){
        float ov = o2l[j];
        dd2 += d2l[j]*ov; so2 += ov*ov;
        float B = b2l[j] - LR*ov; sB2n += B*B;
      }
      unsafeAtomicAdd(&AC[(p*16 + bank)*32 + 3], dd2);
      unsafeAtomicAdd(&AC[(p*16 + bank)*32 + 4], so2);
      unsafeAtomicAdd(&AC[(p*16 + bank)*32 + 5], sB2n);
    }
    // o1 banked partial over owned columns (prefetched s2 row)
    {
      float q0 = s2v0*o2l[0] + s2v1*o2l[1] + s2v2*o2l[2] + s2v3*o2l[3];
      unsafeAtomicAdd(&O1R[(p*NBANK + obank)*HID + tid], q0);
    }
    // ---- Q-arrive: block-wide drain, then bump padded counter ----
    asm volatile("s_waitcnt vmcnt(0) lgkmcnt(0)" ::: "memory");
    __syncthreads();
    if (tid == 0) iadd(&QCNT[CSTR*bank]);
    // ---- Q-wait ----
    {
      const int qtgt = 16*(t+1);
      if (tid < 16){
        while (rload(&QCNT[CSTR*tid]) < qtgt) __builtin_amdgcn_s_sleep(1);
      }
      __syncthreads();
      asm volatile("" ::: "memory");
    }
  }
}

extern "C" void kernel_launch(void* const* d_in, const int* in_sizes, int n_in,
                              void* d_out, int out_size, void* d_ws, size_t ws_size,
                              hipStream_t stream){
  const float* x  = (const float*)d_in[0];
  const float* tg = (const float*)d_in[1];
  const float* w1 = (const float*)d_in[2];
  const float* b1 = (const float*)d_in[3];
  const float* w2 = (const float*)d_in[4];
  const float* b2 = (const float*)d_in[5];
  const float* w3 = (const float*)d_in[6];
  const float* b3 = (const float*)d_in[7];
  float* out = (float*)d_out;
  float* wsf = (float*)d_ws;
  hipLaunchKernelGGL(bp_init,  dim3(NSTEP), dim3(64),  0, stream, x, wsf);
  hipLaunchKernelGGL(bp_train, dim3(NWG),   dim3(TPB), 0, stream,
                     x, tg, w1, b1, w2, b2, w3, b3, out, wsf);
}

// Round 8
// 190485.181 us; speedup vs baseline: 1.0296x; 1.0296x over previous
//
#include <hip/hip_runtime.h>
#include <math.h>

// ---------------------------------------------------------------------------
// Persistent-kernel trainer for the 16384-step sequential MLP scan.
// R17: NWG=128 x CW=8 ported onto the harness-verified R16 skeleton (192k us
// lineage: R12 AC-padding + R15 early-zeroing + R16 hoists/x-pipeline).
// Theory: after 3 flat micro-rounds, residual ~9.5us/step is sync machinery
// scaling with (RMWs/line x pollers/line x straggler count). Halving WGs
// halves ALL of them with same hot-line count (R12 direction, not R13's).
// s1r stays in LDS (32KB at CW=8). Counter targets 16->8 bumps/step.
// Sync protocol otherwise byte-identical. If container fails 2x again,
// the 128-WG shape is abandoned permanently.
// ---------------------------------------------------------------------------

#define NSTEP 16384
#define INDIM 1024
#define HID   1024
#define OUTD  64
#define LR    0.01f
#define EPSN  1e-8f

#define NWG   128
#define TPB   1024
#define CW    8
#define NBANK 8      // O1R banks
#define P3B   8      // P3 banks
#define CSTR  32     // counter stride in ints (128 B)

// workspace layout (float/int indices)
#define OFF_ARRIVE   0                         // 256 ints (init barrier)
#define OFF_RELEASE  512                       // 1 int
#define OFF_PCNT     1024                      // 16 counters, stride 32 ints
#define OFF_QCNT     2048                      // 16 counters, stride 32 ints
#define OFF_U        4096                      // HID floats
#define OFF_O1R      (OFF_U + HID)             // 2*NBANK*HID
#define OFF_P3       (OFF_O1R + 2*NBANK*HID)   // 2*P3B*OUTD
#define OFF_ACC      (OFF_P3 + 2*P3B*OUTD)     // 2*16*32 (banks padded to 128B)
#define OFF_SDOT     (OFF_ACC + 2*16*32)       // NSTEP
#define OFF_NORMX    (OFF_SDOT + NSTEP)        // NSTEP

// ACC slots: 0 m1, 1 m2, 2 m3, 3 dot_d2o2, 4 sum_o2sq, 5 sum_B2sq, 6 sum_a2sq

__device__ __forceinline__ float dload(const float* p){
  return __hip_atomic_load(p, __ATOMIC_RELAXED, __HIP_MEMORY_SCOPE_AGENT);
}
__device__ __forceinline__ void dstore(float* p, float v){
  __hip_atomic_store(p, v, __ATOMIC_RELAXED, __HIP_MEMORY_SCOPE_AGENT);
}
__device__ __forceinline__ int rload(const int* p){
  return __hip_atomic_load(p, __ATOMIC_RELAXED, __HIP_MEMORY_SCOPE_AGENT);
}
__device__ __forceinline__ void rstore(int* p, int v){
  __hip_atomic_store(p, v, __ATOMIC_RELAXED, __HIP_MEMORY_SCOPE_AGENT);
}
__device__ __forceinline__ void iadd(int* p){
  __hip_atomic_fetch_add(p, 1, __ATOMIC_RELAXED, __HIP_MEMORY_SCOPE_AGENT);
}
__device__ __forceinline__ float wredf(float v){
  #pragma unroll
  for (int m = 32; m; m >>= 1) v += __shfl_xor(v, m, 64);
  return v;
}
__device__ __forceinline__ float sigf(float z){ return 1.f/(1.f+__expf(-z)); }

__global__ __launch_bounds__(64) void bp_init(const float* __restrict__ x, float* wsf){
  const int t = blockIdx.x, tid = threadIdx.x;
  const float* xt = x + (size_t)t * INDIM;
  const float* xp = x + (size_t)(t > 0 ? t - 1 : 0) * INDIM;
  float sp = 0.f, nx = 0.f;
  #pragma unroll
  for (int e = 0; e < INDIM/64; e++){
    int i = tid + 64*e; float a = xt[i];
    nx += a*a; sp += a*xp[i];
  }
  sp = wredf(sp); nx = wredf(nx);
  if (tid == 0){ wsf[OFF_SDOT + t] = (t > 0) ? sp : 0.f; wsf[OFF_NORMX + t] = nx; }
  if (blockIdx.x == 0){
    int* wsi = (int*)wsf;
    for (int i = tid; i < 256; i += 64) wsi[OFF_ARRIVE + i] = 0;
    if (tid == 0) wsi[OFF_RELEASE] = 0;
    if (tid < 16){ wsi[OFF_PCNT + CSTR*tid] = 0; wsi[OFF_QCNT + CSTR*tid] = 0; }
    for (int i = tid; i < 2*NBANK*HID; i += 64) wsf[OFF_O1R + i] = 0.f;
    for (int i = tid; i < 2*P3B*OUTD;  i += 64) wsf[OFF_P3 + i]  = 0.f;
    for (int i = tid; i < 2*16*32;     i += 64) wsf[OFF_ACC + i] = 0.f;
    __syncthreads();
    if (tid == 0){
      float* acc1 = wsf + OFF_ACC + 16*32;   // parity-1, bank-0
      acc1[0] = 1.f; acc1[1] = 1.f; acc1[2] = 1.f; acc1[5] = 1.f;
    }
  }
}

__global__ __launch_bounds__(TPB) void bp_train(
    const float* __restrict__ xdat, const float* __restrict__ tgt,
    const float* __restrict__ w1g, const float* __restrict__ b1g,
    const float* __restrict__ w2g, const float* __restrict__ b2g,
    const float* __restrict__ w3g, const float* __restrict__ b3g,
    float* __restrict__ out, float* wsf)
{
  alignas(16) __shared__ float s1r[HID*CW];   // w1 ROW-major: [i][j], 32KB
  alignas(16) __shared__ float s2[CW*HID];    // w2 col-major: [j][i], 32KB
  __shared__ float s3[CW*OUTD];               // w3 rows (8x64)
  alignas(16) __shared__ float a1b[2][HID];
  __shared__ float d1s[HID];
  __shared__ float b1s[HID];
  __shared__ float o1f[HID];
  __shared__ float d3b[2][OUTD];
  __shared__ float p3r[OUTD];
  __shared__ float b3s[OUTD];
  __shared__ float o2l[CW], d2l[CW], b2l[CW];
  __shared__ float a2b[2][CW];
  __shared__ float ascr[256];

  const int tid = threadIdx.x;
  const int wg  = blockIdx.x;
  int*   arrive  = (int*)wsf + OFF_ARRIVE;
  int*   release = (int*)wsf + OFF_RELEASE;
  int*   PCNT    = (int*)wsf + OFF_PCNT;
  int*   QCNT    = (int*)wsf + OFF_QCNT;
  float* U   = wsf + OFF_U;
  float* O1R = wsf + OFF_O1R;
  float* P3  = wsf + OFF_P3;
  float* AC  = wsf + OFF_ACC;
  float* SD  = wsf + OFF_SDOT;
  float* NX  = wsf + OFF_NORMX;
  const int bank  = wg & 15;            // AC / counter bank (8 WGs each)
  const int obank = wg & (NBANK-1);     // O1R bank (16 WGs each)
  const int bank3 = wg & (P3B-1);       // P3 bank (16 WGs each)
  const int wid   = tid >> 6;

  // ---- load owned slices + replicas, zero state ----
  {
    const float4 wa = *reinterpret_cast<const float4*>(&w1g[(size_t)tid*HID + wg*CW]);
    const float4 wb = *reinterpret_cast<const float4*>(&w1g[(size_t)tid*HID + wg*CW + 4]);
    *reinterpret_cast<float4*>(&s1r[8*tid])     = wa;
    *reinterpret_cast<float4*>(&s1r[8*tid + 4]) = wb;
  }
  for (int v = tid; v < CW*HID; v += TPB){
    int j = v & (CW-1); int i = v >> 3;
    s2[j*HID + i] = w2g[(size_t)i*HID + wg*CW + j];
  }
  if (tid < CW*OUTD){
    int i = tid >> 6; int k = tid & 63;
    s3[tid] = w3g[(size_t)(wg*CW + i)*OUTD + k];
  }
  b1s[tid] = b1g[tid]; d1s[tid] = 0.f; o1f[tid] = 0.f; a1b[1][tid] = 0.f;
  if (tid < OUTD){ b3s[tid] = b3g[tid]; d3b[1][tid] = 0.f; p3r[tid] = 0.f; }
  if (tid < CW){
    b2l[tid] = b2g[wg*CW + tid];
    o2l[tid] = 0.f; d2l[tid] = 0.f; a2b[0][tid] = 0.f; a2b[1][tid] = 0.f;
  }
  __syncthreads();

  // x-row register pipeline: xr{0,1} hold rows of x; both start at row 0
  float xr0, xr1;

  // ---- publish u for step 0 ----
  {
    float xv = xdat[tid];
    xr0 = xv; xr1 = xv;
    float4 wa = *reinterpret_cast<const float4*>(&s1r[8*tid]);
    float4 wb = *reinterpret_cast<const float4*>(&s1r[8*tid + 4]);
    float u_[CW];
    u_[0] = wredf(xv*wa.x); u_[1] = wredf(xv*wa.y);
    u_[2] = wredf(xv*wa.z); u_[3] = wredf(xv*wa.w);
    u_[4] = wredf(xv*wb.x); u_[5] = wredf(xv*wb.y);
    u_[6] = wredf(xv*wb.z); u_[7] = wredf(xv*wb.w);
    if ((tid & 63) == 0){
      #pragma unroll
      for (int c = 0; c < CW; c++) ascr[96 + wid*CW + c] = u_[c];
    }
    __syncthreads();
    if (tid < CW){
      float s = 0.f;
      #pragma unroll
      for (int w2_ = 0; w2_ < 16; w2_++) s += ascr[96 + w2_*CW + tid];
      dstore(&U[wg*CW + tid], s);
    }
  }
  // initial full funnel barrier (once)
  {
    asm volatile("s_waitcnt vmcnt(0) lgkmcnt(0)" ::: "memory");
    __syncthreads();
    if (tid == 0) rstore(&arrive[wg], 1);
    if (wg == 0){
      if (tid < NWG){ while (rload(&arrive[tid]) < 1) __builtin_amdgcn_s_sleep(1); }
      __syncthreads();
      if (tid == 0) rstore(release, 1);
    }
    if (tid == 0){ while (rload(release) < 1) __builtin_amdgcn_s_sleep(1); }
    __syncthreads();
    asm volatile("" ::: "memory");
  }

  for (int t = 0; t <= NSTEP; t++){
    const int p = t & 1, qq = p ^ 1;
    float* a1c = a1b[p];  float* a1p = a1b[qq];
    float* a2c = a2b[p];  float* a2p = a2b[qq];
    float* d3c = d3b[p];  float* d3p = d3b[qq];

    // ================= Phase A =================
    // hoisted cold loads (issued early, consumed later)
    float nxp = NX[t > 0 ? t - 1 : 0];
    float sdt = SD[t < NSTEP ? t : 0];
    float tv_pf = (t < NSTEP && tid < OUTD) ? tgt[(size_t)t*OUTD + tid] : 0.f;

    if (tid < 112){
      int s = tid >> 4, b = tid & 15;
      ascr[128 + s*16 + b] = dload(&AC[(qq*16 + b)*32 + s]);
    }
    float u0 = dload(&U[tid]);
    float r0 = 0.f;
    #pragma unroll
    for (int b = 0; b < NBANK; b++)
      r0 += dload(&O1R[(qq*NBANK + b)*HID + tid]);
    float a1p0 = a1p[tid];
    float of0 = r0 * a1p0 * (1.f - a1p0);
    o1f[tid] = of0;

    // stage 2: per-wave partials
    {
      float v0 = d1s[tid]*of0;
      float v1 = of0*of0;
      float Ba = b1s[tid] - LR*of0;
      float v2 = Ba*Ba;
      float v3 = a1p0*a1p0;
      v0 = wredf(v0); v1 = wredf(v1); v2 = wredf(v2); v3 = wredf(v3);
      if ((tid & 63) == 0){
        ascr[0*16+wid]=v0; ascr[1*16+wid]=v1; ascr[2*16+wid]=v2; ascr[3*16+wid]=v3;
      }
      if (tid < 64){
        float d3v = d3p[tid];
        float v4 = d3v*d3v;
        float B3 = b3s[tid] - LR*d3v; float v5 = B3*B3;
        float v6 = d3v * p3r[tid];
        v4 = wredf(v4); v5 = wredf(v5); v6 = wredf(v6);
        if (tid == 0){ ascr[244]=v4; ascr[245]=v5; ascr[246]=v6; }
      }
    }
    __syncthreads();
    if (tid < 64){
      if (tid < 4){
        float s = 0.f;
        #pragma unroll
        for (int w = 0; w < 16; w++) s += ascr[tid*16 + w];
        ascr[240 + tid] = s;
      } else if (tid >= 8 && tid < 15){
        int s_ = tid - 8;
        float s = 0.f;
        #pragma unroll
        for (int b = 0; b < 16; b++) s += ascr[128 + s_*16 + b];
        ascr[248 + s_] = s;
      }
    }
    __syncthreads();
    float dd  = ascr[240], so  = ascr[241], sb  = ascr[242], sa1 = ascr[243];
    float sd3 = ascr[244], sb3 = ascr[245], dp3 = ascr[246];
    float m1p = ascr[248], m2p = ascr[249], m3p = ascr[250], dq  = ascr[251];
    float soq = ascr[252], sB2 = ascr[253], sa2 = ascr[254];

    float n1  = fmaxf(sqrtf(fmaxf(m1p - 2.f*LR*dd  + LR*LR*nxp*so,  0.f)), EPSN);
    float nb1 = fmaxf(sqrtf(sb),  EPSN);
    float n2  = fmaxf(sqrtf(fmaxf(m2p - 2.f*LR*dq  + LR*LR*sa1*soq, 0.f)), EPSN);
    float nb2 = fmaxf(sqrtf(sB2), EPSN);
    float n3  = fmaxf(sqrtf(fmaxf(m3p - 2.f*LR*dp3 + LR*LR*sa2*sd3, 0.f)), EPSN);
    float nb3 = fmaxf(sqrtf(sb3), EPSN);
    float rn1 = 1.f/n1, rnb1 = 1.f/nb1, rn2 = 1.f/n2, rnb2 = 1.f/nb2;
    float rn3 = 1.f/n3, rnb3 = 1.f/nb3;

    // stage 3
    {
      float B0 = (b1s[tid] - LR*of0)*rnb1; b1s[tid] = B0;
      float dn0 = (u0 - LR*of0*sdt)*rn1;   d1s[tid] = dn0;
      a1c[tid] = sigf(dn0 + B0);
    }
    __syncthreads();

    // stage 4: fused W2 update + matvec (cols j and j+4 per thread)
    {
      int j = tid >> 8, l = tid & 255;
      float coefA = LR * o2l[j];
      float coefB = LR * o2l[j+4];
      float4 wa = *reinterpret_cast<float4*>(&s2[j*HID + 4*l]);
      float4 wb = *reinterpret_cast<float4*>(&s2[(j+4)*HID + 4*l]);
      float4 ap = *reinterpret_cast<const float4*>(&a1p[4*l]);
      float4 ac = *reinterpret_cast<const float4*>(&a1c[4*l]);
      wa.x = (wa.x - coefA*ap.x)*rn2;  wa.y = (wa.y - coefA*ap.y)*rn2;
      wa.z = (wa.z - coefA*ap.z)*rn2;  wa.w = (wa.w - coefA*ap.w)*rn2;
      wb.x = (wb.x - coefB*ap.x)*rn2;  wb.y = (wb.y - coefB*ap.y)*rn2;
      wb.z = (wb.z - coefB*ap.z)*rn2;  wb.w = (wb.w - coefB*ap.w)*rn2;
      *reinterpret_cast<float4*>(&s2[j*HID + 4*l])     = wa;
      *reinterpret_cast<float4*>(&s2[(j+4)*HID + 4*l]) = wb;
      float accA = ac.x*wa.x + ac.y*wa.y + ac.z*wa.z + ac.w*wa.w;
      float accB = ac.x*wb.x + ac.y*wb.y + ac.z*wb.z + ac.w*wb.w;
      float ms   = wa.x*wa.x + wa.y*wa.y + wa.z*wa.z + wa.w*wa.w
                 + wb.x*wb.x + wb.y*wb.y + wb.z*wb.z + wb.w*wb.w;
      accA = wredf(accA); accB = wredf(accB); ms = wredf(ms);
      if ((tid & 63) == 0){ ascr[wid] = accA; ascr[32 + wid] = accB; ascr[16 + wid] = ms; }
    }
    __syncthreads();
    if (tid < CW){
      float d2;
      if (tid < 4)
        d2 = ascr[4*tid] + ascr[4*tid+1] + ascr[4*tid+2] + ascr[4*tid+3];
      else {
        int b = 32 + 4*(tid-4);
        d2 = ascr[b] + ascr[b+1] + ascr[b+2] + ascr[b+3];
      }
      d2l[tid] = d2;
      float b2n = (b2l[tid] - LR*o2l[tid])*rnb2;
      b2l[tid] = b2n;
      a2c[tid] = sigf(d2 + b2n);
    }
    __syncthreads();
    // off wave0: keeps wave0's P-arrive drain P3-only (Q-gated slots)
    if (tid == 64){
      float m2 = 0.f;
      #pragma unroll
      for (int w = 0; w < 16; w++) m2 += ascr[16 + w];
      unsafeAtomicAdd(&AC[(p*16 + bank)*32 + 1], m2);
      float s = 0.f;
      for (int j = 0; j < CW; j++){ float a = a2c[j]; s += a*a; }
      unsafeAtomicAdd(&AC[(p*16 + bank)*32 + 6], s);
    }

    // stage 5: fused W3 update + P3 publish (wave0 only)
    if (tid < OUTD){
      int k = tid;
      float d3k = d3p[k];
      float contrib = 0.f, m3s = 0.f;
      #pragma unroll
      for (int i = 0; i < CW; i++){
        float w = s3[i*OUTD + k];
        w = (w - LR*a2p[i]*d3k)*rn3;
        s3[i*OUTD + k] = w;
        contrib += a2c[i]*w;
        m3s += w*w;
      }
      unsafeAtomicAdd(&P3[(p*P3B + bank3)*OUTD + k], contrib);
      m3s = wredf(m3s);
      if (k == 0) unsafeAtomicAdd(&AC[(p*16 + bank)*32 + 2], m3s);
      b3s[k] = (b3s[k] - LR*d3k)*rnb3;
    }

    // ===== epilogue =====
    if (t == NSTEP){
      __syncthreads();
      const float* xl = xdat + (size_t)(NSTEP - 1)*INDIM;
      float xv = xl[tid];
      float c0 = LR*o1f[wg*CW+0], c1 = LR*o1f[wg*CW+1];
      float c2 = LR*o1f[wg*CW+2], c3 = LR*o1f[wg*CW+3];
      float c4 = LR*o1f[wg*CW+4], c5 = LR*o1f[wg*CW+5];
      float c6 = LR*o1f[wg*CW+6], c7 = LR*o1f[wg*CW+7];
      float4 wa = *reinterpret_cast<const float4*>(&s1r[8*tid]);
      float4 wb = *reinterpret_cast<const float4*>(&s1r[8*tid + 4]);
      float4 ovA, ovB;
      ovA.x = (wa.x - c0*xv)*rn1; ovA.y = (wa.y - c1*xv)*rn1;
      ovA.z = (wa.z - c2*xv)*rn1; ovA.w = (wa.w - c3*xv)*rn1;
      ovB.x = (wb.x - c4*xv)*rn1; ovB.y = (wb.y - c5*xv)*rn1;
      ovB.z = (wb.z - c6*xv)*rn1; ovB.w = (wb.w - c7*xv)*rn1;
      *reinterpret_cast<float4*>(&out[(size_t)tid*HID + wg*CW])     = ovA;
      *reinterpret_cast<float4*>(&out[(size_t)tid*HID + wg*CW + 4]) = ovB;
      float4 o2a, o2b;
      o2a.x = s2[0*HID+tid]; o2a.y = s2[1*HID+tid];
      o2a.z = s2[2*HID+tid]; o2a.w = s2[3*HID+tid];
      o2b.x = s2[4*HID+tid]; o2b.y = s2[5*HID+tid];
      o2b.z = s2[6*HID+tid]; o2b.w = s2[7*HID+tid];
      *reinterpret_cast<float4*>(&out[(size_t)HID*HID + (size_t)tid*HID + wg*CW])     = o2a;
      *reinterpret_cast<float4*>(&out[(size_t)HID*HID + (size_t)tid*HID + wg*CW + 4]) = o2b;
      if (tid < OUTD){
        #pragma unroll
        for (int i = 0; i < CW; i++)
          out[(size_t)2*HID*HID + (size_t)(wg*CW + i)*OUTD + tid] = s3[i*OUTD + tid];
      }
      break;
    }

    // ---- P-arrive: all P-side publishes are wave0's atomics ----
    if (wid == 0){
      asm volatile("s_waitcnt vmcnt(0) lgkmcnt(0)" ::: "memory");
      if (tid == 0) iadd(&PCNT[CSTR*bank]);
    }

    // ---- shadow (WG-local): fused W1 update + u_{t+1} partials + m1 ----
    float u_pub = 0.f;
    {
      const float* xn_ = xdat + (size_t)(t + 1 < NSTEP ? t + 1 : NSTEP - 1)*INDIM;
      float xpv = (t & 1) ? xr0 : xr1;   // row t-1, loaded 2 steps ago
      float xnv = xn_[tid];
      if (t & 1) xr0 = xnv; else xr1 = xnv;
      float c0 = LR*o1f[wg*CW+0], c1 = LR*o1f[wg*CW+1];
      float c2 = LR*o1f[wg*CW+2], c3 = LR*o1f[wg*CW+3];
      float c4 = LR*o1f[wg*CW+4], c5 = LR*o1f[wg*CW+5];
      float c6 = LR*o1f[wg*CW+6], c7 = LR*o1f[wg*CW+7];
      float4 wa = *reinterpret_cast<float4*>(&s1r[8*tid]);
      float4 wb = *reinterpret_cast<float4*>(&s1r[8*tid + 4]);
      wa.x = (wa.x - c0*xpv)*rn1; wa.y = (wa.y - c1*xpv)*rn1;
      wa.z = (wa.z - c2*xpv)*rn1; wa.w = (wa.w - c3*xpv)*rn1;
      wb.x = (wb.x - c4*xpv)*rn1; wb.y = (wb.y - c5*xpv)*rn1;
      wb.z = (wb.z - c6*xpv)*rn1; wb.w = (wb.w - c7*xpv)*rn1;
      *reinterpret_cast<float4*>(&s1r[8*tid])     = wa;
      *reinterpret_cast<float4*>(&s1r[8*tid + 4]) = wb;
      float m1s = wa.x*wa.x + wa.y*wa.y + wa.z*wa.z + wa.w*wa.w
                + wb.x*wb.x + wb.y*wb.y + wb.z*wb.z + wb.w*wb.w;
      float u_[CW];
      u_[0] = wredf(xnv*wa.x); u_[1] = wredf(xnv*wa.y);
      u_[2] = wredf(xnv*wa.z); u_[3] = wredf(xnv*wa.w);
      u_[4] = wredf(xnv*wb.x); u_[5] = wredf(xnv*wb.y);
      u_[6] = wredf(xnv*wb.z); u_[7] = wredf(xnv*wb.w);
      m1s = wredf(m1s);
      if ((tid & 63) == 0){
        #pragma unroll
        for (int c = 0; c < CW; c++) ascr[96 + wid*CW + c] = u_[c];
        ascr[224 + wid] = m1s;
      }
      __syncthreads();
      if (tid < CW){
        float s = 0.f;
        #pragma unroll
        for (int w2_ = 0; w2_ < 16; w2_++) s += ascr[96 + w2_*CW + tid];
        u_pub = s;
      }
      if (tid == 0){
        float m1 = 0.f;
        #pragma unroll
        for (int w2_ = 0; w2_ < 16; w2_++) m1 += ascr[224 + w2_];
        unsafeAtomicAdd(&AC[(p*16 + bank)*32 + 0], m1);
      }
    }

    // ---- P-wait: poll 16 padded producer counters (one line each) ----
    {
      const int ptgt = (NWG/16)*(t+1);
      if (tid < 16){
        while (rload(&PCNT[CSTR*tid]) < ptgt) __builtin_amdgcn_s_sleep(1);
      }
      __syncthreads();
      asm volatile("" ::: "memory");
    }

    // ================= Phase B =================
    // early zeroing of next-parity accumulators (safe: P-wait proves all WGs
    // consumed their Phase-A qq reads); acks overlap Phase B compute
    if (wg < NBANK) dstore(&O1R[(qq*NBANK + wg)*HID + tid], 0.f);
    if (wg < P3B && tid < OUTD) dstore(&P3[(qq*P3B + wg)*OUTD + tid], 0.f);
    if (wg < 16  && tid < 8)    dstore(&AC[(qq*16 + wg)*32 + tid], 0.f);
    if (tid < CW) dstore(&U[wg*CW + tid], u_pub);   // safe: all WGs past A stage1
    // prefetch s2 row (stable since stage 4) for the o1 partial
    float s2v0 = s2[0*HID+tid], s2v1 = s2[1*HID+tid];
    float s2v2 = s2[2*HID+tid], s2v3 = s2[3*HID+tid];
    float s2v4 = s2[4*HID+tid], s2v5 = s2[5*HID+tid];
    float s2v6 = s2[6*HID+tid], s2v7 = s2[7*HID+tid];

    if (tid < OUTD){
      float s = 0.f;
      #pragma unroll
      for (int b = 0; b < P3B; b++) s += dload(&P3[(p*P3B + b)*OUTD + tid]);
      p3r[tid] = s;
      float a3 = sigf(s + b3s[tid]);
      float e3 = __expf(-a3);
      float es = wredf(e3);
      float net = e3 / es;
      d3c[tid] = (tv_pf - net) * a3 * (1.f - a3);
    }
    __syncthreads();
    if (tid < CW*OUTD){
      int i = tid >> 6, k = tid & 63;
      float v = wredf(s3[i*OUTD + k] * d3c[k]);
      if (k == 0){ float a2v = a2c[i]; o2l[i] = v * a2v * (1.f - a2v); }
    }
    __syncthreads();
    if (tid == 0){
      float dd2 = 0.f, so2 = 0.f, sB2n = 0.f;
      for (int j = 0; j < CW; j++){
        float ov = o2l[j];
        dd2 += d2l[j]*ov; so2 += ov*ov;
        float B = b2l[j] - LR*ov; sB2n += B*B;
      }
      unsafeAtomicAdd(&AC[(p*16 + bank)*32 + 3], dd2);
      unsafeAtomicAdd(&AC[(p*16 + bank)*32 + 4], so2);
      unsafeAtomicAdd(&AC[(p*16 + bank)*32 + 5], sB2n);
    }
    // o1 banked partial over owned columns (prefetched s2 row)
    {
      float q0 = s2v0*o2l[0] + s2v1*o2l[1] + s2v2*o2l[2] + s2v3*o2l[3]
               + s2v4*o2l[4] + s2v5*o2l[5] + s2v6*o2l[6] + s2v7*o2l[7];
      unsafeAtomicAdd(&O1R[(p*NBANK + obank)*HID + tid], q0);
    }
    // ---- Q-arrive: block-wide drain, then bump padded counter ----
    asm volatile("s_waitcnt vmcnt(0) lgkmcnt(0)" ::: "memory");
    __syncthreads();
    if (tid == 0) iadd(&QCNT[CSTR*bank]);
    // ---- Q-wait ----
    {
      const int qtgt = (NWG/16)*(t+1);
      if (tid < 16){
        while (rload(&QCNT[CSTR*tid]) < qtgt) __builtin_amdgcn_s_sleep(1);
      }
      __syncthreads();
      asm volatile("" ::: "memory");
    }
  }
}

extern "C" void kernel_launch(void* const* d_in, const int* in_sizes, int n_in,
                              void* d_out, int out_size, void* d_ws, size_t ws_size,
                              hipStream_t stream){
  const float* x  = (const float*)d_in[0];
  const float* tg = (const float*)d_in[1];
  const float* w1 = (const float*)d_in[2];
  const float* b1 = (const float*)d_in[3];
  const float* w2 = (const float*)d_in[4];
  const float* b2 = (const float*)d_in[5];
  const float* w3 = (const float*)d_in[6];
  const float* b3 = (const float*)d_in[7];
  float* out = (float*)d_out;
  float* wsf = (float*)d_ws;
  hipLaunchKernelGGL(bp_init,  dim3(NSTEP), dim3(64),  0, stream, x, wsf);
  hipLaunchKernelGGL(bp_train, dim3(NWG),   dim3(TPB), 0, stream,
                     x, tg, w1, b1, w2, b2, w3, b3, out, wsf);
}

// Round 9
// 188071.826 us; speedup vs baseline: 1.0428x; 1.0128x over previous
//
#include <hip/hip_runtime.h>
#include <math.h>

// ---------------------------------------------------------------------------
// Persistent-kernel trainer for the 16384-step sequential MLP scan.
// R18: R17 (128 WG x CW=8, 190.5k us) + two safe fixes, no sync edits.
//  1) s1r split into s1a/s1b (cols 0-3 / 4-7), each float4 @ 4*tid (16B
//     stride) -- kills the 16-way LDS bank conflict R17 introduced
//     (SQ_LDS_BANK_CONFLICT 98K -> 8.06e8; stride-32B b128 = 16-way).
//  2) Phase-A issue reorder: O1R/U loads first (feed of0, first consumer),
//     then AC staging (hidden under stage 2), then cold hoists.
// R17 decision-rule outcome: WRITE halved, dur flat -> floor is RTT-chain
// latency, not contention. These fixes trim the residual local costs.
// ---------------------------------------------------------------------------

#define NSTEP 16384
#define INDIM 1024
#define HID   1024
#define OUTD  64
#define LR    0.01f
#define EPSN  1e-8f

#define NWG   128
#define TPB   1024
#define CW    8
#define NBANK 8      // O1R banks
#define P3B   8      // P3 banks
#define CSTR  32     // counter stride in ints (128 B)

// workspace layout (float/int indices)
#define OFF_ARRIVE   0                         // 256 ints (init barrier)
#define OFF_RELEASE  512                       // 1 int
#define OFF_PCNT     1024                      // 16 counters, stride 32 ints
#define OFF_QCNT     2048                      // 16 counters, stride 32 ints
#define OFF_U        4096                      // HID floats
#define OFF_O1R      (OFF_U + HID)             // 2*NBANK*HID
#define OFF_P3       (OFF_O1R + 2*NBANK*HID)   // 2*P3B*OUTD
#define OFF_ACC      (OFF_P3 + 2*P3B*OUTD)     // 2*16*32 (banks padded to 128B)
#define OFF_SDOT     (OFF_ACC + 2*16*32)       // NSTEP
#define OFF_NORMX    (OFF_SDOT + NSTEP)        // NSTEP

// ACC slots: 0 m1, 1 m2, 2 m3, 3 dot_d2o2, 4 sum_o2sq, 5 sum_B2sq, 6 sum_a2sq

__device__ __forceinline__ float dload(const float* p){
  return __hip_atomic_load(p, __ATOMIC_RELAXED, __HIP_MEMORY_SCOPE_AGENT);
}
__device__ __forceinline__ void dstore(float* p, float v){
  __hip_atomic_store(p, v, __ATOMIC_RELAXED, __HIP_MEMORY_SCOPE_AGENT);
}
__device__ __forceinline__ int rload(const int* p){
  return __hip_atomic_load(p, __ATOMIC_RELAXED, __HIP_MEMORY_SCOPE_AGENT);
}
__device__ __forceinline__ void rstore(int* p, int v){
  __hip_atomic_store(p, v, __ATOMIC_RELAXED, __HIP_MEMORY_SCOPE_AGENT);
}
__device__ __forceinline__ void iadd(int* p){
  __hip_atomic_fetch_add(p, 1, __ATOMIC_RELAXED, __HIP_MEMORY_SCOPE_AGENT);
}
__device__ __forceinline__ float wredf(float v){
  #pragma unroll
  for (int m = 32; m; m >>= 1) v += __shfl_xor(v, m, 64);
  return v;
}
__device__ __forceinline__ float sigf(float z){ return 1.f/(1.f+__expf(-z)); }

__global__ __launch_bounds__(64) void bp_init(const float* __restrict__ x, float* wsf){
  const int t = blockIdx.x, tid = threadIdx.x;
  const float* xt = x + (size_t)t * INDIM;
  const float* xp = x + (size_t)(t > 0 ? t - 1 : 0) * INDIM;
  float sp = 0.f, nx = 0.f;
  #pragma unroll
  for (int e = 0; e < INDIM/64; e++){
    int i = tid + 64*e; float a = xt[i];
    nx += a*a; sp += a*xp[i];
  }
  sp = wredf(sp); nx = wredf(nx);
  if (tid == 0){ wsf[OFF_SDOT + t] = (t > 0) ? sp : 0.f; wsf[OFF_NORMX + t] = nx; }
  if (blockIdx.x == 0){
    int* wsi = (int*)wsf;
    for (int i = tid; i < 256; i += 64) wsi[OFF_ARRIVE + i] = 0;
    if (tid == 0) wsi[OFF_RELEASE] = 0;
    if (tid < 16){ wsi[OFF_PCNT + CSTR*tid] = 0; wsi[OFF_QCNT + CSTR*tid] = 0; }
    for (int i = tid; i < 2*NBANK*HID; i += 64) wsf[OFF_O1R + i] = 0.f;
    for (int i = tid; i < 2*P3B*OUTD;  i += 64) wsf[OFF_P3 + i]  = 0.f;
    for (int i = tid; i < 2*16*32;     i += 64) wsf[OFF_ACC + i] = 0.f;
    __syncthreads();
    if (tid == 0){
      float* acc1 = wsf + OFF_ACC + 16*32;   // parity-1, bank-0
      acc1[0] = 1.f; acc1[1] = 1.f; acc1[2] = 1.f; acc1[5] = 1.f;
    }
  }
}

__global__ __launch_bounds__(TPB) void bp_train(
    const float* __restrict__ xdat, const float* __restrict__ tgt,
    const float* __restrict__ w1g, const float* __restrict__ b1g,
    const float* __restrict__ w2g, const float* __restrict__ b2g,
    const float* __restrict__ w3g, const float* __restrict__ b3g,
    float* __restrict__ out, float* wsf)
{
  alignas(16) __shared__ float s1a[HID*4];    // w1 cols [wg*CW, wg*CW+4)
  alignas(16) __shared__ float s1b[HID*4];    // w1 cols [wg*CW+4, wg*CW+8)
  alignas(16) __shared__ float s2[CW*HID];    // w2 col-major: [j][i], 32KB
  __shared__ float s3[CW*OUTD];               // w3 rows (8x64)
  alignas(16) __shared__ float a1b[2][HID];
  __shared__ float d1s[HID];
  __shared__ float b1s[HID];
  __shared__ float o1f[HID];
  __shared__ float d3b[2][OUTD];
  __shared__ float p3r[OUTD];
  __shared__ float b3s[OUTD];
  __shared__ float o2l[CW], d2l[CW], b2l[CW];
  __shared__ float a2b[2][CW];
  __shared__ float ascr[256];

  const int tid = threadIdx.x;
  const int wg  = blockIdx.x;
  int*   arrive  = (int*)wsf + OFF_ARRIVE;
  int*   release = (int*)wsf + OFF_RELEASE;
  int*   PCNT    = (int*)wsf + OFF_PCNT;
  int*   QCNT    = (int*)wsf + OFF_QCNT;
  float* U   = wsf + OFF_U;
  float* O1R = wsf + OFF_O1R;
  float* P3  = wsf + OFF_P3;
  float* AC  = wsf + OFF_ACC;
  float* SD  = wsf + OFF_SDOT;
  float* NX  = wsf + OFF_NORMX;
  const int bank  = wg & 15;            // AC / counter bank (8 WGs each)
  const int obank = wg & (NBANK-1);     // O1R bank (16 WGs each)
  const int bank3 = wg & (P3B-1);       // P3 bank (16 WGs each)
  const int wid   = tid >> 6;

  // ---- load owned slices + replicas, zero state ----
  {
    const float4 wa = *reinterpret_cast<const float4*>(&w1g[(size_t)tid*HID + wg*CW]);
    const float4 wb = *reinterpret_cast<const float4*>(&w1g[(size_t)tid*HID + wg*CW + 4]);
    *reinterpret_cast<float4*>(&s1a[4*tid]) = wa;
    *reinterpret_cast<float4*>(&s1b[4*tid]) = wb;
  }
  for (int v = tid; v < CW*HID; v += TPB){
    int j = v & (CW-1); int i = v >> 3;
    s2[j*HID + i] = w2g[(size_t)i*HID + wg*CW + j];
  }
  if (tid < CW*OUTD){
    int i = tid >> 6; int k = tid & 63;
    s3[tid] = w3g[(size_t)(wg*CW + i)*OUTD + k];
  }
  b1s[tid] = b1g[tid]; d1s[tid] = 0.f; o1f[tid] = 0.f; a1b[1][tid] = 0.f;
  if (tid < OUTD){ b3s[tid] = b3g[tid]; d3b[1][tid] = 0.f; p3r[tid] = 0.f; }
  if (tid < CW){
    b2l[tid] = b2g[wg*CW + tid];
    o2l[tid] = 0.f; d2l[tid] = 0.f; a2b[0][tid] = 0.f; a2b[1][tid] = 0.f;
  }
  __syncthreads();

  // x-row register pipeline: xr{0,1} hold rows of x; both start at row 0
  float xr0, xr1;

  // ---- publish u for step 0 ----
  {
    float xv = xdat[tid];
    xr0 = xv; xr1 = xv;
    float4 wa = *reinterpret_cast<const float4*>(&s1a[4*tid]);
    float4 wb = *reinterpret_cast<const float4*>(&s1b[4*tid]);
    float u_[CW];
    u_[0] = wredf(xv*wa.x); u_[1] = wredf(xv*wa.y);
    u_[2] = wredf(xv*wa.z); u_[3] = wredf(xv*wa.w);
    u_[4] = wredf(xv*wb.x); u_[5] = wredf(xv*wb.y);
    u_[6] = wredf(xv*wb.z); u_[7] = wredf(xv*wb.w);
    if ((tid & 63) == 0){
      #pragma unroll
      for (int c = 0; c < CW; c++) ascr[96 + wid*CW + c] = u_[c];
    }
    __syncthreads();
    if (tid < CW){
      float s = 0.f;
      #pragma unroll
      for (int w2_ = 0; w2_ < 16; w2_++) s += ascr[96 + w2_*CW + tid];
      dstore(&U[wg*CW + tid], s);
    }
  }
  // initial full funnel barrier (once)
  {
    asm volatile("s_waitcnt vmcnt(0) lgkmcnt(0)" ::: "memory");
    __syncthreads();
    if (tid == 0) rstore(&arrive[wg], 1);
    if (wg == 0){
      if (tid < NWG){ while (rload(&arrive[tid]) < 1) __builtin_amdgcn_s_sleep(1); }
      __syncthreads();
      if (tid == 0) rstore(release, 1);
    }
    if (tid == 0){ while (rload(release) < 1) __builtin_amdgcn_s_sleep(1); }
    __syncthreads();
    asm volatile("" ::: "memory");
  }

  for (int t = 0; t <= NSTEP; t++){
    const int p = t & 1, qq = p ^ 1;
    float* a1c = a1b[p];  float* a1p = a1b[qq];
    float* a2c = a2b[p];  float* a2p = a2b[qq];
    float* d3c = d3b[p];  float* d3p = d3b[qq];

    // ================= Phase A =================
    // O1R + U first: they feed of0, the first consumer on the critical path
    float u0 = dload(&U[tid]);
    float r0 = 0.f;
    #pragma unroll
    for (int b = 0; b < NBANK; b++)
      r0 += dload(&O1R[(qq*NBANK + b)*HID + tid]);
    // AC staging: consumed after stage 2 (latency hidden under wredf chains)
    if (tid < 112){
      int s = tid >> 4, b = tid & 15;
      ascr[128 + s*16 + b] = dload(&AC[(qq*16 + b)*32 + s]);
    }
    // cold hoists: consumed last (norm math / Phase B)
    float nxp = NX[t > 0 ? t - 1 : 0];
    float sdt = SD[t < NSTEP ? t : 0];
    float tv_pf = (t < NSTEP && tid < OUTD) ? tgt[(size_t)t*OUTD + tid] : 0.f;

    float a1p0 = a1p[tid];
    float of0 = r0 * a1p0 * (1.f - a1p0);
    o1f[tid] = of0;

    // stage 2: per-wave partials
    {
      float v0 = d1s[tid]*of0;
      float v1 = of0*of0;
      float Ba = b1s[tid] - LR*of0;
      float v2 = Ba*Ba;
      float v3 = a1p0*a1p0;
      v0 = wredf(v0); v1 = wredf(v1); v2 = wredf(v2); v3 = wredf(v3);
      if ((tid & 63) == 0){
        ascr[0*16+wid]=v0; ascr[1*16+wid]=v1; ascr[2*16+wid]=v2; ascr[3*16+wid]=v3;
      }
      if (tid < 64){
        float d3v = d3p[tid];
        float v4 = d3v*d3v;
        float B3 = b3s[tid] - LR*d3v; float v5 = B3*B3;
        float v6 = d3v * p3r[tid];
        v4 = wredf(v4); v5 = wredf(v5); v6 = wredf(v6);
        if (tid == 0){ ascr[244]=v4; ascr[245]=v5; ascr[246]=v6; }
      }
    }
    __syncthreads();
    if (tid < 64){
      if (tid < 4){
        float s = 0.f;
        #pragma unroll
        for (int w = 0; w < 16; w++) s += ascr[tid*16 + w];
        ascr[240 + tid] = s;
      } else if (tid >= 8 && tid < 15){
        int s_ = tid - 8;
        float s = 0.f;
        #pragma unroll
        for (int b = 0; b < 16; b++) s += ascr[128 + s_*16 + b];
        ascr[248 + s_] = s;
      }
    }
    __syncthreads();
    float dd  = ascr[240], so  = ascr[241], sb  = ascr[242], sa1 = ascr[243];
    float sd3 = ascr[244], sb3 = ascr[245], dp3 = ascr[246];
    float m1p = ascr[248], m2p = ascr[249], m3p = ascr[250], dq  = ascr[251];
    float soq = ascr[252], sB2 = ascr[253], sa2 = ascr[254];

    float n1  = fmaxf(sqrtf(fmaxf(m1p - 2.f*LR*dd  + LR*LR*nxp*so,  0.f)), EPSN);
    float nb1 = fmaxf(sqrtf(sb),  EPSN);
    float n2  = fmaxf(sqrtf(fmaxf(m2p - 2.f*LR*dq  + LR*LR*sa1*soq, 0.f)), EPSN);
    float nb2 = fmaxf(sqrtf(sB2), EPSN);
    float n3  = fmaxf(sqrtf(fmaxf(m3p - 2.f*LR*dp3 + LR*LR*sa2*sd3, 0.f)), EPSN);
    float nb3 = fmaxf(sqrtf(sb3), EPSN);
    float rn1 = 1.f/n1, rnb1 = 1.f/nb1, rn2 = 1.f/n2, rnb2 = 1.f/nb2;
    float rn3 = 1.f/n3, rnb3 = 1.f/nb3;

    // stage 3
    {
      float B0 = (b1s[tid] - LR*of0)*rnb1; b1s[tid] = B0;
      float dn0 = (u0 - LR*of0*sdt)*rn1;   d1s[tid] = dn0;
      a1c[tid] = sigf(dn0 + B0);
    }
    __syncthreads();

    // stage 4: fused W2 update + matvec (cols j and j+4 per thread)
    {
      int j = tid >> 8, l = tid & 255;
      float coefA = LR * o2l[j];
      float coefB = LR * o2l[j+4];
      float4 wa = *reinterpret_cast<float4*>(&s2[j*HID + 4*l]);
      float4 wb = *reinterpret_cast<float4*>(&s2[(j+4)*HID + 4*l]);
      float4 ap = *reinterpret_cast<const float4*>(&a1p[4*l]);
      float4 ac = *reinterpret_cast<const float4*>(&a1c[4*l]);
      wa.x = (wa.x - coefA*ap.x)*rn2;  wa.y = (wa.y - coefA*ap.y)*rn2;
      wa.z = (wa.z - coefA*ap.z)*rn2;  wa.w = (wa.w - coefA*ap.w)*rn2;
      wb.x = (wb.x - coefB*ap.x)*rn2;  wb.y = (wb.y - coefB*ap.y)*rn2;
      wb.z = (wb.z - coefB*ap.z)*rn2;  wb.w = (wb.w - coefB*ap.w)*rn2;
      *reinterpret_cast<float4*>(&s2[j*HID + 4*l])     = wa;
      *reinterpret_cast<float4*>(&s2[(j+4)*HID + 4*l]) = wb;
      float accA = ac.x*wa.x + ac.y*wa.y + ac.z*wa.z + ac.w*wa.w;
      float accB = ac.x*wb.x + ac.y*wb.y + ac.z*wb.z + ac.w*wb.w;
      float ms   = wa.x*wa.x + wa.y*wa.y + wa.z*wa.z + wa.w*wa.w
                 + wb.x*wb.x + wb.y*wb.y + wb.z*wb.z + wb.w*wb.w;
      accA = wredf(accA); accB = wredf(accB); ms = wredf(ms);
      if ((tid & 63) == 0){ ascr[wid] = accA; ascr[32 + wid] = accB; ascr[16 + wid] = ms; }
    }
    __syncthreads();
    if (tid < CW){
      float d2;
      if (tid < 4)
        d2 = ascr[4*tid] + ascr[4*tid+1] + ascr[4*tid+2] + ascr[4*tid+3];
      else {
        int b = 32 + 4*(tid-4);
        d2 = ascr[b] + ascr[b+1] + ascr[b+2] + ascr[b+3];
      }
      d2l[tid] = d2;
      float b2n = (b2l[tid] - LR*o2l[tid])*rnb2;
      b2l[tid] = b2n;
      a2c[tid] = sigf(d2 + b2n);
    }
    __syncthreads();
    // off wave0: keeps wave0's P-arrive drain P3-only (Q-gated slots)
    if (tid == 64){
      float m2 = 0.f;
      #pragma unroll
      for (int w = 0; w < 16; w++) m2 += ascr[16 + w];
      unsafeAtomicAdd(&AC[(p*16 + bank)*32 + 1], m2);
      float s = 0.f;
      for (int j = 0; j < CW; j++){ float a = a2c[j]; s += a*a; }
      unsafeAtomicAdd(&AC[(p*16 + bank)*32 + 6], s);
    }

    // stage 5: fused W3 update + P3 publish (wave0 only)
    if (tid < OUTD){
      int k = tid;
      float d3k = d3p[k];
      float contrib = 0.f, m3s = 0.f;
      #pragma unroll
      for (int i = 0; i < CW; i++){
        float w = s3[i*OUTD + k];
        w = (w - LR*a2p[i]*d3k)*rn3;
        s3[i*OUTD + k] = w;
        contrib += a2c[i]*w;
        m3s += w*w;
      }
      unsafeAtomicAdd(&P3[(p*P3B + bank3)*OUTD + k], contrib);
      m3s = wredf(m3s);
      if (k == 0) unsafeAtomicAdd(&AC[(p*16 + bank)*32 + 2], m3s);
      b3s[k] = (b3s[k] - LR*d3k)*rnb3;
    }

    // ===== epilogue =====
    if (t == NSTEP){
      __syncthreads();
      const float* xl = xdat + (size_t)(NSTEP - 1)*INDIM;
      float xv = xl[tid];
      float c0 = LR*o1f[wg*CW+0], c1 = LR*o1f[wg*CW+1];
      float c2 = LR*o1f[wg*CW+2], c3 = LR*o1f[wg*CW+3];
      float c4 = LR*o1f[wg*CW+4], c5 = LR*o1f[wg*CW+5];
      float c6 = LR*o1f[wg*CW+6], c7 = LR*o1f[wg*CW+7];
      float4 wa = *reinterpret_cast<const float4*>(&s1a[4*tid]);
      float4 wb = *reinterpret_cast<const float4*>(&s1b[4*tid]);
      float4 ovA, ovB;
      ovA.x = (wa.x - c0*xv)*rn1; ovA.y = (wa.y - c1*xv)*rn1;
      ovA.z = (wa.z - c2*xv)*rn1; ovA.w = (wa.w - c3*xv)*rn1;
      ovB.x = (wb.x - c4*xv)*rn1; ovB.y = (wb.y - c5*xv)*rn1;
      ovB.z = (wb.z - c6*xv)*rn1; ovB.w = (wb.w - c7*xv)*rn1;
      *reinterpret_cast<float4*>(&out[(size_t)tid*HID + wg*CW])     = ovA;
      *reinterpret_cast<float4*>(&out[(size_t)tid*HID + wg*CW + 4]) = ovB;
      float4 o2a, o2b;
      o2a.x = s2[0*HID+tid]; o2a.y = s2[1*HID+tid];
      o2a.z = s2[2*HID+tid]; o2a.w = s2[3*HID+tid];
      o2b.x = s2[4*HID+tid]; o2b.y = s2[5*HID+tid];
      o2b.z = s2[6*HID+tid]; o2b.w = s2[7*HID+tid];
      *reinterpret_cast<float4*>(&out[(size_t)HID*HID + (size_t)tid*HID + wg*CW])     = o2a;
      *reinterpret_cast<float4*>(&out[(size_t)HID*HID + (size_t)tid*HID + wg*CW + 4]) = o2b;
      if (tid < OUTD){
        #pragma unroll
        for (int i = 0; i < CW; i++)
          out[(size_t)2*HID*HID + (size_t)(wg*CW + i)*OUTD + tid] = s3[i*OUTD + tid];
      }
      break;
    }

    // ---- P-arrive: all P-side publishes are wave0's atomics ----
    if (wid == 0){
      asm volatile("s_waitcnt vmcnt(0) lgkmcnt(0)" ::: "memory");
      if (tid == 0) iadd(&PCNT[CSTR*bank]);
    }

    // ---- shadow (WG-local): fused W1 update + u_{t+1} partials + m1 ----
    float u_pub = 0.f;
    {
      const float* xn_ = xdat + (size_t)(t + 1 < NSTEP ? t + 1 : NSTEP - 1)*INDIM;
      float xpv = (t & 1) ? xr0 : xr1;   // row t-1, loaded 2 steps ago
      float xnv = xn_[tid];
      if (t & 1) xr0 = xnv; else xr1 = xnv;
      float c0 = LR*o1f[wg*CW+0], c1 = LR*o1f[wg*CW+1];
      float c2 = LR*o1f[wg*CW+2], c3 = LR*o1f[wg*CW+3];
      float c4 = LR*o1f[wg*CW+4], c5 = LR*o1f[wg*CW+5];
      float c6 = LR*o1f[wg*CW+6], c7 = LR*o1f[wg*CW+7];
      float4 wa = *reinterpret_cast<float4*>(&s1a[4*tid]);
      float4 wb = *reinterpret_cast<float4*>(&s1b[4*tid]);
      wa.x = (wa.x - c0*xpv)*rn1; wa.y = (wa.y - c1*xpv)*rn1;
      wa.z = (wa.z - c2*xpv)*rn1; wa.w = (wa.w - c3*xpv)*rn1;
      wb.x = (wb.x - c4*xpv)*rn1; wb.y = (wb.y - c5*xpv)*rn1;
      wb.z = (wb.z - c6*xpv)*rn1; wb.w = (wb.w - c7*xpv)*rn1;
      *reinterpret_cast<float4*>(&s1a[4*tid]) = wa;
      *reinterpret_cast<float4*>(&s1b[4*tid]) = wb;
      float m1s = wa.x*wa.x + wa.y*wa.y + wa.z*wa.z + wa.w*wa.w
                + wb.x*wb.x + wb.y*wb.y + wb.z*wb.z + wb.w*wb.w;
      float u_[CW];
      u_[0] = wredf(xnv*wa.x); u_[1] = wredf(xnv*wa.y);
      u_[2] = wredf(xnv*wa.z); u_[3] = wredf(xnv*wa.w);
      u_[4] = wredf(xnv*wb.x); u_[5] = wredf(xnv*wb.y);
      u_[6] = wredf(xnv*wb.z); u_[7] = wredf(xnv*wb.w);
      m1s = wredf(m1s);
      if ((tid & 63) == 0){
        #pragma unroll
        for (int c = 0; c < CW; c++) ascr[96 + wid*CW + c] = u_[c];
        ascr[224 + wid] = m1s;
      }
      __syncthreads();
      if (tid < CW){
        float s = 0.f;
        #pragma unroll
        for (int w2_ = 0; w2_ < 16; w2_++) s += ascr[96 + w2_*CW + tid];
        u_pub = s;
      }
      if (tid == 0){
        float m1 = 0.f;
        #pragma unroll
        for (int w2_ = 0; w2_ < 16; w2_++) m1 += ascr[224 + w2_];
        unsafeAtomicAdd(&AC[(p*16 + bank)*32 + 0], m1);
      }
    }

    // ---- P-wait: poll 16 padded producer counters (one line each) ----
    {
      const int ptgt = (NWG/16)*(t+1);
      if (tid < 16){
        while (rload(&PCNT[CSTR*tid]) < ptgt) __builtin_amdgcn_s_sleep(1);
      }
      __syncthreads();
      asm volatile("" ::: "memory");
    }

    // ================= Phase B =================
    // early zeroing of next-parity accumulators (safe: P-wait proves all WGs
    // consumed their Phase-A qq reads); acks overlap Phase B compute
    if (wg < NBANK) dstore(&O1R[(qq*NBANK + wg)*HID + tid], 0.f);
    if (wg < P3B && tid < OUTD) dstore(&P3[(qq*P3B + wg)*OUTD + tid], 0.f);
    if (wg < 16  && tid < 8)    dstore(&AC[(qq*16 + wg)*32 + tid], 0.f);
    if (tid < CW) dstore(&U[wg*CW + tid], u_pub);   // safe: all WGs past A stage1
    // prefetch s2 row (stable since stage 4) for the o1 partial
    float s2v0 = s2[0*HID+tid], s2v1 = s2[1*HID+tid];
    float s2v2 = s2[2*HID+tid], s2v3 = s2[3*HID+tid];
    float s2v4 = s2[4*HID+tid], s2v5 = s2[5*HID+tid];
    float s2v6 = s2[6*HID+tid], s2v7 = s2[7*HID+tid];

    if (tid < OUTD){
      float s = 0.f;
      #pragma unroll
      for (int b = 0; b < P3B; b++) s += dload(&P3[(p*P3B + b)*OUTD + tid]);
      p3r[tid] = s;
      float a3 = sigf(s + b3s[tid]);
      float e3 = __expf(-a3);
      float es = wredf(e3);
      float net = e3 / es;
      d3c[tid] = (tv_pf - net) * a3 * (1.f - a3);
    }
    __syncthreads();
    if (tid < CW*OUTD){
      int i = tid >> 6, k = tid & 63;
      float v = wredf(s3[i*OUTD + k] * d3c[k]);
      if (k == 0){ float a2v = a2c[i]; o2l[i] = v * a2v * (1.f - a2v); }
    }
    __syncthreads();
    if (tid == 0){
      float dd2 = 0.f, so2 = 0.f, sB2n = 0.f;
      for (int j = 0; j < CW; j++){
        float ov = o2l[j];
        dd2 += d2l[j]*ov; so2 += ov*ov;
        float B = b2l[j] - LR*ov; sB2n += B*B;
      }
      unsafeAtomicAdd(&AC[(p*16 + bank)*32 + 3], dd2);
      unsafeAtomicAdd(&AC[(p*16 + bank)*32 + 4], so2);
      unsafeAtomicAdd(&AC[(p*16 + bank)*32 + 5], sB2n);
    }
    // o1 banked partial over owned columns (prefetched s2 row)
    {
      float q0 = s2v0*o2l[0] + s2v1*o2l[1] + s2v2*o2l[2] + s2v3*o2l[3]
               + s2v4*o2l[4] + s2v5*o2l[5] + s2v6*o2l[6] + s2v7*o2l[7];
      unsafeAtomicAdd(&O1R[(p*NBANK + obank)*HID + tid], q0);
    }
    // ---- Q-arrive: block-wide drain, then bump padded counter ----
    asm volatile("s_waitcnt vmcnt(0) lgkmcnt(0)" ::: "memory");
    __syncthreads();
    if (tid == 0) iadd(&QCNT[CSTR*bank]);
    // ---- Q-wait ----
    {
      const int qtgt = (NWG/16)*(t+1);
      if (tid < 16){
        while (rload(&QCNT[CSTR*tid]) < qtgt) __builtin_amdgcn_s_sleep(1);
      }
      __syncthreads();
      asm volatile("" ::: "memory");
    }
  }
}

extern "C" void kernel_launch(void* const* d_in, const int* in_sizes, int n_in,
                              void* d_out, int out_size, void* d_ws, size_t ws_size,
                              hipStream_t stream){
  const float* x  = (const float*)d_in[0];
  const float* tg = (const float*)d_in[1];
  const float* w1 = (const float*)d_in[2];
  const float* b1 = (const float*)d_in[3];
  const float* w2 = (const float*)d_in[4];
  const float* b2 = (const float*)d_in[5];
  const float* w3 = (const float*)d_in[6];
  const float* b3 = (const float*)d_in[7];
  float* out = (float*)d_out;
  float* wsf = (float*)d_ws;
  hipLaunchKernelGGL(bp_init,  dim3(NSTEP), dim3(64),  0, stream, x, wsf);
  hipLaunchKernelGGL(bp_train, dim3(NWG),   dim3(TPB), 0, stream,
                     x, tg, w1, b1, w2, b2, w3, b3, out, wsf);
}

// Round 11
// 177770.691 us; speedup vs baseline: 1.1033x; 1.0579x over previous
//
#include <hip/hip_runtime.h>
#include <math.h>

// ---------------------------------------------------------------------------
// Persistent-kernel trainer for the 16384-step sequential MLP scan.
// R20 == R19 resubmitted (round-10 bench died to container/infra failure;
// audit of all three changes found no defect; precedent: R17 == R10/R11's
// shape passed after R10/R11 failed twice each). Fill the naked Q-hop window:
//  1) cold hoists for t+1 (NX, SD, tgt row) -> loop-carried regs
//  2) x-row load (row t+2) -> pre-Q (xnv_pre), off the shadow path
//  3) stage-2 tid<64 trio (v4,v5,v6 from d3c/b3s/p3r, all final by end of
//     Phase B) -> pre-Q into ascr[244..246]; deleted from Phase A.
//     Slot audit: no writer touches 244-246 between pre-Q(t) and read(t+1).
// Base: R18 (128WG x CW=8, s1a/s1b split, NBANK=8, P3B=8, AC 128B-padded,
// 188.1k us). Sync protocol untouched.
// ---------------------------------------------------------------------------

#define NSTEP 16384
#define INDIM 1024
#define HID   1024
#define OUTD  64
#define LR    0.01f
#define EPSN  1e-8f

#define NWG   128
#define TPB   1024
#define CW    8
#define NBANK 8      // O1R banks
#define P3B   8      // P3 banks
#define CSTR  32     // counter stride in ints (128 B)

// workspace layout (float/int indices)
#define OFF_ARRIVE   0                         // 256 ints (init barrier)
#define OFF_RELEASE  512                       // 1 int
#define OFF_PCNT     1024                      // 16 counters, stride 32 ints
#define OFF_QCNT     2048                      // 16 counters, stride 32 ints
#define OFF_U        4096                      // HID floats
#define OFF_O1R      (OFF_U + HID)             // 2*NBANK*HID
#define OFF_P3       (OFF_O1R + 2*NBANK*HID)   // 2*P3B*OUTD
#define OFF_ACC      (OFF_P3 + 2*P3B*OUTD)     // 2*16*32 (banks padded to 128B)
#define OFF_SDOT     (OFF_ACC + 2*16*32)       // NSTEP
#define OFF_NORMX    (OFF_SDOT + NSTEP)        // NSTEP

// ACC slots: 0 m1, 1 m2, 2 m3, 3 dot_d2o2, 4 sum_o2sq, 5 sum_B2sq, 6 sum_a2sq

__device__ __forceinline__ float dload(const float* p){
  return __hip_atomic_load(p, __ATOMIC_RELAXED, __HIP_MEMORY_SCOPE_AGENT);
}
__device__ __forceinline__ void dstore(float* p, float v){
  __hip_atomic_store(p, v, __ATOMIC_RELAXED, __HIP_MEMORY_SCOPE_AGENT);
}
__device__ __forceinline__ int rload(const int* p){
  return __hip_atomic_load(p, __ATOMIC_RELAXED, __HIP_MEMORY_SCOPE_AGENT);
}
__device__ __forceinline__ void rstore(int* p, int v){
  __hip_atomic_store(p, v, __ATOMIC_RELAXED, __HIP_MEMORY_SCOPE_AGENT);
}
__device__ __forceinline__ void iadd(int* p){
  __hip_atomic_fetch_add(p, 1, __ATOMIC_RELAXED, __HIP_MEMORY_SCOPE_AGENT);
}
__device__ __forceinline__ float wredf(float v){
  #pragma unroll
  for (int m = 32; m; m >>= 1) v += __shfl_xor(v, m, 64);
  return v;
}
__device__ __forceinline__ float sigf(float z){ return 1.f/(1.f+__expf(-z)); }

__global__ __launch_bounds__(64) void bp_init(const float* __restrict__ x, float* wsf){
  const int t = blockIdx.x, tid = threadIdx.x;
  const float* xt = x + (size_t)t * INDIM;
  const float* xp = x + (size_t)(t > 0 ? t - 1 : 0) * INDIM;
  float sp = 0.f, nx = 0.f;
  #pragma unroll
  for (int e = 0; e < INDIM/64; e++){
    int i = tid + 64*e; float a = xt[i];
    nx += a*a; sp += a*xp[i];
  }
  sp = wredf(sp); nx = wredf(nx);
  if (tid == 0){ wsf[OFF_SDOT + t] = (t > 0) ? sp : 0.f; wsf[OFF_NORMX + t] = nx; }
  if (blockIdx.x == 0){
    int* wsi = (int*)wsf;
    for (int i = tid; i < 256; i += 64) wsi[OFF_ARRIVE + i] = 0;
    if (tid == 0) wsi[OFF_RELEASE] = 0;
    if (tid < 16){ wsi[OFF_PCNT + CSTR*tid] = 0; wsi[OFF_QCNT + CSTR*tid] = 0; }
    for (int i = tid; i < 2*NBANK*HID; i += 64) wsf[OFF_O1R + i] = 0.f;
    for (int i = tid; i < 2*P3B*OUTD;  i += 64) wsf[OFF_P3 + i]  = 0.f;
    for (int i = tid; i < 2*16*32;     i += 64) wsf[OFF_ACC + i] = 0.f;
    __syncthreads();
    if (tid == 0){
      float* acc1 = wsf + OFF_ACC + 16*32;   // parity-1, bank-0
      acc1[0] = 1.f; acc1[1] = 1.f; acc1[2] = 1.f; acc1[5] = 1.f;
    }
  }
}

__global__ __launch_bounds__(TPB) void bp_train(
    const float* __restrict__ xdat, const float* __restrict__ tgt,
    const float* __restrict__ w1g, const float* __restrict__ b1g,
    const float* __restrict__ w2g, const float* __restrict__ b2g,
    const float* __restrict__ w3g, const float* __restrict__ b3g,
    float* __restrict__ out, float* wsf)
{
  alignas(16) __shared__ float s1a[HID*4];    // w1 cols [wg*CW, wg*CW+4)
  alignas(16) __shared__ float s1b[HID*4];    // w1 cols [wg*CW+4, wg*CW+8)
  alignas(16) __shared__ float s2[CW*HID];    // w2 col-major: [j][i], 32KB
  __shared__ float s3[CW*OUTD];               // w3 rows (8x64)
  alignas(16) __shared__ float a1b[2][HID];
  __shared__ float d1s[HID];
  __shared__ float b1s[HID];
  __shared__ float o1f[HID];
  __shared__ float d3b[2][OUTD];
  __shared__ float p3r[OUTD];
  __shared__ float b3s[OUTD];
  __shared__ float o2l[CW], d2l[CW], b2l[CW];
  __shared__ float a2b[2][CW];
  __shared__ float ascr[256];

  const int tid = threadIdx.x;
  const int wg  = blockIdx.x;
  int*   arrive  = (int*)wsf + OFF_ARRIVE;
  int*   release = (int*)wsf + OFF_RELEASE;
  int*   PCNT    = (int*)wsf + OFF_PCNT;
  int*   QCNT    = (int*)wsf + OFF_QCNT;
  float* U   = wsf + OFF_U;
  float* O1R = wsf + OFF_O1R;
  float* P3  = wsf + OFF_P3;
  float* AC  = wsf + OFF_ACC;
  float* SD  = wsf + OFF_SDOT;
  float* NX  = wsf + OFF_NORMX;
  const int bank  = wg & 15;            // AC / counter bank (8 WGs each)
  const int obank = wg & (NBANK-1);     // O1R bank (16 WGs each)
  const int bank3 = wg & (P3B-1);       // P3 bank (16 WGs each)
  const int wid   = tid >> 6;

  // ---- load owned slices + replicas, zero state ----
  {
    const float4 wa = *reinterpret_cast<const float4*>(&w1g[(size_t)tid*HID + wg*CW]);
    const float4 wb = *reinterpret_cast<const float4*>(&w1g[(size_t)tid*HID + wg*CW + 4]);
    *reinterpret_cast<float4*>(&s1a[4*tid]) = wa;
    *reinterpret_cast<float4*>(&s1b[4*tid]) = wb;
  }
  for (int v = tid; v < CW*HID; v += TPB){
    int j = v & (CW-1); int i = v >> 3;
    s2[j*HID + i] = w2g[(size_t)i*HID + wg*CW + j];
  }
  if (tid < CW*OUTD){
    int i = tid >> 6; int k = tid & 63;
    s3[tid] = w3g[(size_t)(wg*CW + i)*OUTD + k];
  }
  b1s[tid] = b1g[tid]; d1s[tid] = 0.f; o1f[tid] = 0.f; a1b[1][tid] = 0.f;
  if (tid < OUTD){ b3s[tid] = b3g[tid]; d3b[1][tid] = 0.f; p3r[tid] = 0.f; }
  if (tid < CW){
    b2l[tid] = b2g[wg*CW + tid];
    o2l[tid] = 0.f; d2l[tid] = 0.f; a2b[0][tid] = 0.f; a2b[1][tid] = 0.f;
  }
  __syncthreads();

  // x-row register pipeline: xr{0,1} hold rows of x; both start at row 0
  float xr0, xr1;
  // loop-carried prefetch registers (updated in the pre-Q window)
  float nxp, sdt, tv_pf, xnv_pre;

  // ---- publish u for step 0 ----
  {
    float xv = xdat[tid];
    xr0 = xv; xr1 = xv;
    float4 wa = *reinterpret_cast<const float4*>(&s1a[4*tid]);
    float4 wb = *reinterpret_cast<const float4*>(&s1b[4*tid]);
    float u_[CW];
    u_[0] = wredf(xv*wa.x); u_[1] = wredf(xv*wa.y);
    u_[2] = wredf(xv*wa.z); u_[3] = wredf(xv*wa.w);
    u_[4] = wredf(xv*wb.x); u_[5] = wredf(xv*wb.y);
    u_[6] = wredf(xv*wb.z); u_[7] = wredf(xv*wb.w);
    if ((tid & 63) == 0){
      #pragma unroll
      for (int c = 0; c < CW; c++) ascr[96 + wid*CW + c] = u_[c];
    }
    __syncthreads();
    if (tid < CW){
      float s = 0.f;
      #pragma unroll
      for (int w2_ = 0; w2_ < 16; w2_++) s += ascr[96 + w2_*CW + tid];
      dstore(&U[wg*CW + tid], s);
    }
  }
  // ---- prologue prefetch for t=0 + initial trio (ascr[244..246]) ----
  {
    nxp = NX[0]; sdt = SD[0];
    tv_pf = (tid < OUTD) ? tgt[tid] : 0.f;
    xnv_pre = xdat[(size_t)1*INDIM + tid];         // row 1 for shadow(0)
    if (tid < 64){
      float d3v = d3b[1][tid];                      // zeros at init
      float v4 = d3v*d3v;
      float B3 = b3s[tid] - LR*d3v; float v5 = B3*B3;
      float v6 = d3v * p3r[tid];
      v4 = wredf(v4); v5 = wredf(v5); v6 = wredf(v6);
      if (tid == 0){ ascr[244]=v4; ascr[245]=v5; ascr[246]=v6; }
    }
  }
  // initial full funnel barrier (once)
  {
    asm volatile("s_waitcnt vmcnt(0) lgkmcnt(0)" ::: "memory");
    __syncthreads();
    if (tid == 0) rstore(&arrive[wg], 1);
    if (wg == 0){
      if (tid < NWG){ while (rload(&arrive[tid]) < 1) __builtin_amdgcn_s_sleep(1); }
      __syncthreads();
      if (tid == 0) rstore(release, 1);
    }
    if (tid == 0){ while (rload(release) < 1) __builtin_amdgcn_s_sleep(1); }
    __syncthreads();
    asm volatile("" ::: "memory");
  }

  for (int t = 0; t <= NSTEP; t++){
    const int p = t & 1, qq = p ^ 1;
    float* a1c = a1b[p];  float* a1p = a1b[qq];
    float* a2c = a2b[p];  float* a2p = a2b[qq];
    float* d3c = d3b[p];  float* d3p = d3b[qq];

    // ================= Phase A =================
    // O1R + U first: they feed of0, the first consumer on the critical path
    float u0 = dload(&U[tid]);
    float r0 = 0.f;
    #pragma unroll
    for (int b = 0; b < NBANK; b++)
      r0 += dload(&O1R[(qq*NBANK + b)*HID + tid]);
    // AC staging: consumed after stage 2 (latency hidden under wredf chains)
    if (tid < 112){
      int s = tid >> 4, b = tid & 15;
      ascr[128 + s*16 + b] = dload(&AC[(qq*16 + b)*32 + s]);
    }

    float a1p0 = a1p[tid];
    float of0 = r0 * a1p0 * (1.f - a1p0);
    o1f[tid] = of0;

    // stage 2: per-wave partials (tid<64 trio now computed pre-Q last step)
    {
      float v0 = d1s[tid]*of0;
      float v1 = of0*of0;
      float Ba = b1s[tid] - LR*of0;
      float v2 = Ba*Ba;
      float v3 = a1p0*a1p0;
      v0 = wredf(v0); v1 = wredf(v1); v2 = wredf(v2); v3 = wredf(v3);
      if ((tid & 63) == 0){
        ascr[0*16+wid]=v0; ascr[1*16+wid]=v1; ascr[2*16+wid]=v2; ascr[3*16+wid]=v3;
      }
    }
    __syncthreads();
    if (tid < 64){
      if (tid < 4){
        float s = 0.f;
        #pragma unroll
        for (int w = 0; w < 16; w++) s += ascr[tid*16 + w];
        ascr[240 + tid] = s;
      } else if (tid >= 8 && tid < 15){
        int s_ = tid - 8;
        float s = 0.f;
        #pragma unroll
        for (int b = 0; b < 16; b++) s += ascr[128 + s_*16 + b];
        ascr[248 + s_] = s;
      }
    }
    __syncthreads();
    float dd  = ascr[240], so  = ascr[241], sb  = ascr[242], sa1 = ascr[243];
    float sd3 = ascr[244], sb3 = ascr[245], dp3 = ascr[246];
    float m1p = ascr[248], m2p = ascr[249], m3p = ascr[250], dq  = ascr[251];
    float soq = ascr[252], sB2 = ascr[253], sa2 = ascr[254];

    float n1  = fmaxf(sqrtf(fmaxf(m1p - 2.f*LR*dd  + LR*LR*nxp*so,  0.f)), EPSN);
    float nb1 = fmaxf(sqrtf(sb),  EPSN);
    float n2  = fmaxf(sqrtf(fmaxf(m2p - 2.f*LR*dq  + LR*LR*sa1*soq, 0.f)), EPSN);
    float nb2 = fmaxf(sqrtf(sB2), EPSN);
    float n3  = fmaxf(sqrtf(fmaxf(m3p - 2.f*LR*dp3 + LR*LR*sa2*sd3, 0.f)), EPSN);
    float nb3 = fmaxf(sqrtf(sb3), EPSN);
    float rn1 = 1.f/n1, rnb1 = 1.f/nb1, rn2 = 1.f/n2, rnb2 = 1.f/nb2;
    float rn3 = 1.f/n3, rnb3 = 1.f/nb3;

    // stage 3
    {
      float B0 = (b1s[tid] - LR*of0)*rnb1; b1s[tid] = B0;
      float dn0 = (u0 - LR*of0*sdt)*rn1;   d1s[tid] = dn0;
      a1c[tid] = sigf(dn0 + B0);
    }
    __syncthreads();

    // stage 4: fused W2 update + matvec (cols j and j+4 per thread)
    {
      int j = tid >> 8, l = tid & 255;
      float coefA = LR * o2l[j];
      float coefB = LR * o2l[j+4];
      float4 wa = *reinterpret_cast<float4*>(&s2[j*HID + 4*l]);
      float4 wb = *reinterpret_cast<float4*>(&s2[(j+4)*HID + 4*l]);
      float4 ap = *reinterpret_cast<const float4*>(&a1p[4*l]);
      float4 ac = *reinterpret_cast<const float4*>(&a1c[4*l]);
      wa.x = (wa.x - coefA*ap.x)*rn2;  wa.y = (wa.y - coefA*ap.y)*rn2;
      wa.z = (wa.z - coefA*ap.z)*rn2;  wa.w = (wa.w - coefA*ap.w)*rn2;
      wb.x = (wb.x - coefB*ap.x)*rn2;  wb.y = (wb.y - coefB*ap.y)*rn2;
      wb.z = (wb.z - coefB*ap.z)*rn2;  wb.w = (wb.w - coefB*ap.w)*rn2;
      *reinterpret_cast<float4*>(&s2[j*HID + 4*l])     = wa;
      *reinterpret_cast<float4*>(&s2[(j+4)*HID + 4*l]) = wb;
      float accA = ac.x*wa.x + ac.y*wa.y + ac.z*wa.z + ac.w*wa.w;
      float accB = ac.x*wb.x + ac.y*wb.y + ac.z*wb.z + ac.w*wb.w;
      float ms   = wa.x*wa.x + wa.y*wa.y + wa.z*wa.z + wa.w*wa.w
                 + wb.x*wb.x + wb.y*wb.y + wb.z*wb.z + wb.w*wb.w;
      accA = wredf(accA); accB = wredf(accB); ms = wredf(ms);
      if ((tid & 63) == 0){ ascr[wid] = accA; ascr[32 + wid] = accB; ascr[16 + wid] = ms; }
    }
    __syncthreads();
    if (tid < CW){
      float d2;
      if (tid < 4)
        d2 = ascr[4*tid] + ascr[4*tid+1] + ascr[4*tid+2] + ascr[4*tid+3];
      else {
        int b = 32 + 4*(tid-4);
        d2 = ascr[b] + ascr[b+1] + ascr[b+2] + ascr[b+3];
      }
      d2l[tid] = d2;
      float b2n = (b2l[tid] - LR*o2l[tid])*rnb2;
      b2l[tid] = b2n;
      a2c[tid] = sigf(d2 + b2n);
    }
    __syncthreads();
    // off wave0: keeps wave0's P-arrive drain P3-only (Q-gated slots)
    if (tid == 64){
      float m2 = 0.f;
      #pragma unroll
      for (int w = 0; w < 16; w++) m2 += ascr[16 + w];
      unsafeAtomicAdd(&AC[(p*16 + bank)*32 + 1], m2);
      float s = 0.f;
      for (int j = 0; j < CW; j++){ float a = a2c[j]; s += a*a; }
      unsafeAtomicAdd(&AC[(p*16 + bank)*32 + 6], s);
    }

    // stage 5: fused W3 update + P3 publish (wave0 only)
    if (tid < OUTD){
      int k = tid;
      float d3k = d3p[k];
      float contrib = 0.f, m3s = 0.f;
      #pragma unroll
      for (int i = 0; i < CW; i++){
        float w = s3[i*OUTD + k];
        w = (w - LR*a2p[i]*d3k)*rn3;
        s3[i*OUTD + k] = w;
        contrib += a2c[i]*w;
        m3s += w*w;
      }
      unsafeAtomicAdd(&P3[(p*P3B + bank3)*OUTD + k], contrib);
      m3s = wredf(m3s);
      if (k == 0) unsafeAtomicAdd(&AC[(p*16 + bank)*32 + 2], m3s);
      b3s[k] = (b3s[k] - LR*d3k)*rnb3;
    }

    // ===== epilogue =====
    if (t == NSTEP){
      __syncthreads();
      const float* xl = xdat + (size_t)(NSTEP - 1)*INDIM;
      float xv = xl[tid];
      float c0 = LR*o1f[wg*CW+0], c1 = LR*o1f[wg*CW+1];
      float c2 = LR*o1f[wg*CW+2], c3 = LR*o1f[wg*CW+3];
      float c4 = LR*o1f[wg*CW+4], c5 = LR*o1f[wg*CW+5];
      float c6 = LR*o1f[wg*CW+6], c7 = LR*o1f[wg*CW+7];
      float4 wa = *reinterpret_cast<const float4*>(&s1a[4*tid]);
      float4 wb = *reinterpret_cast<const float4*>(&s1b[4*tid]);
      float4 ovA, ovB;
      ovA.x = (wa.x - c0*xv)*rn1; ovA.y = (wa.y - c1*xv)*rn1;
      ovA.z = (wa.z - c2*xv)*rn1; ovA.w = (wa.w - c3*xv)*rn1;
      ovB.x = (wb.x - c4*xv)*rn1; ovB.y = (wb.y - c5*xv)*rn1;
      ovB.z = (wb.z - c6*xv)*rn1; ovB.w = (wb.w - c7*xv)*rn1;
      *reinterpret_cast<float4*>(&out[(size_t)tid*HID + wg*CW])     = ovA;
      *reinterpret_cast<float4*>(&out[(size_t)tid*HID + wg*CW + 4]) = ovB;
      float4 o2a, o2b;
      o2a.x = s2[0*HID+tid]; o2a.y = s2[1*HID+tid];
      o2a.z = s2[2*HID+tid]; o2a.w = s2[3*HID+tid];
      o2b.x = s2[4*HID+tid]; o2b.y = s2[5*HID+tid];
      o2b.z = s2[6*HID+tid]; o2b.w = s2[7*HID+tid];
      *reinterpret_cast<float4*>(&out[(size_t)HID*HID + (size_t)tid*HID + wg*CW])     = o2a;
      *reinterpret_cast<float4*>(&out[(size_t)HID*HID + (size_t)tid*HID + wg*CW + 4]) = o2b;
      if (tid < OUTD){
        #pragma unroll
        for (int i = 0; i < CW; i++)
          out[(size_t)2*HID*HID + (size_t)(wg*CW + i)*OUTD + tid] = s3[i*OUTD + tid];
      }
      break;
    }

    // ---- P-arrive: all P-side publishes are wave0's atomics ----
    if (wid == 0){
      asm volatile("s_waitcnt vmcnt(0) lgkmcnt(0)" ::: "memory");
      if (tid == 0) iadd(&PCNT[CSTR*bank]);
    }

    // ---- shadow (WG-local): fused W1 update + u_{t+1} partials + m1 ----
    float u_pub = 0.f;
    {
      float xpv = (t & 1) ? xr0 : xr1;   // row t-1, loaded 2 steps ago
      float xnv = xnv_pre;               // row t+1, loaded in pre-Q window
      if (t & 1) xr0 = xnv; else xr1 = xnv;
      float c0 = LR*o1f[wg*CW+0], c1 = LR*o1f[wg*CW+1];
      float c2 = LR*o1f[wg*CW+2], c3 = LR*o1f[wg*CW+3];
      float c4 = LR*o1f[wg*CW+4], c5 = LR*o1f[wg*CW+5];
      float c6 = LR*o1f[wg*CW+6], c7 = LR*o1f[wg*CW+7];
      float4 wa = *reinterpret_cast<float4*>(&s1a[4*tid]);
      float4 wb = *reinterpret_cast<float4*>(&s1b[4*tid]);
      wa.x = (wa.x - c0*xpv)*rn1; wa.y = (wa.y - c1*xpv)*rn1;
      wa.z = (wa.z - c2*xpv)*rn1; wa.w = (wa.w - c3*xpv)*rn1;
      wb.x = (wb.x - c4*xpv)*rn1; wb.y = (wb.y - c5*xpv)*rn1;
      wb.z = (wb.z - c6*xpv)*rn1; wb.w = (wb.w - c7*xpv)*rn1;
      *reinterpret_cast<float4*>(&s1a[4*tid]) = wa;
      *reinterpret_cast<float4*>(&s1b[4*tid]) = wb;
      float m1s = wa.x*wa.x + wa.y*wa.y + wa.z*wa.z + wa.w*wa.w
                + wb.x*wb.x + wb.y*wb.y + wb.z*wb.z + wb.w*wb.w;
      float u_[CW];
      u_[0] = wredf(xnv*wa.x); u_[1] = wredf(xnv*wa.y);
      u_[2] = wredf(xnv*wa.z); u_[3] = wredf(xnv*wa.w);
      u_[4] = wredf(xnv*wb.x); u_[5] = wredf(xnv*wb.y);
      u_[6] = wredf(xnv*wb.z); u_[7] = wredf(xnv*wb.w);
      m1s = wredf(m1s);
      if ((tid & 63) == 0){
        #pragma unroll
        for (int c = 0; c < CW; c++) ascr[96 + wid*CW + c] = u_[c];
        ascr[224 + wid] = m1s;
      }
      __syncthreads();
      if (tid < CW){
        float s = 0.f;
        #pragma unroll
        for (int w2_ = 0; w2_ < 16; w2_++) s += ascr[96 + w2_*CW + tid];
        u_pub = s;
      }
      if (tid == 0){
        float m1 = 0.f;
        #pragma unroll
        for (int w2_ = 0; w2_ < 16; w2_++) m1 += ascr[224 + w2_];
        unsafeAtomicAdd(&AC[(p*16 + bank)*32 + 0], m1);
      }
    }

    // ---- P-wait: poll 16 padded producer counters (one line each) ----
    {
      const int ptgt = (NWG/16)*(t+1);
      if (tid < 16){
        while (rload(&PCNT[CSTR*tid]) < ptgt) __builtin_amdgcn_s_sleep(1);
      }
      __syncthreads();
      asm volatile("" ::: "memory");
    }

    // ================= Phase B =================
    // early zeroing of next-parity accumulators (safe: P-wait proves all WGs
    // consumed their Phase-A qq reads); acks overlap Phase B compute
    if (wg < NBANK) dstore(&O1R[(qq*NBANK + wg)*HID + tid], 0.f);
    if (wg < P3B && tid < OUTD) dstore(&P3[(qq*P3B + wg)*OUTD + tid], 0.f);
    if (wg < 16  && tid < 8)    dstore(&AC[(qq*16 + wg)*32 + tid], 0.f);
    if (tid < CW) dstore(&U[wg*CW + tid], u_pub);   // safe: all WGs past A stage1
    // prefetch s2 row (stable since stage 4) for the o1 partial
    float s2v0 = s2[0*HID+tid], s2v1 = s2[1*HID+tid];
    float s2v2 = s2[2*HID+tid], s2v3 = s2[3*HID+tid];
    float s2v4 = s2[4*HID+tid], s2v5 = s2[5*HID+tid];
    float s2v6 = s2[6*HID+tid], s2v7 = s2[7*HID+tid];

    if (tid < OUTD){
      float s = 0.f;
      #pragma unroll
      for (int b = 0; b < P3B; b++) s += dload(&P3[(p*P3B + b)*OUTD + tid]);
      p3r[tid] = s;
      float a3 = sigf(s + b3s[tid]);
      float e3 = __expf(-a3);
      float es = wredf(e3);
      float net = e3 / es;
      d3c[tid] = (tv_pf - net) * a3 * (1.f - a3);
    }
    __syncthreads();
    if (tid < CW*OUTD){
      int i = tid >> 6, k = tid & 63;
      float v = wredf(s3[i*OUTD + k] * d3c[k]);
      if (k == 0){ float a2v = a2c[i]; o2l[i] = v * a2v * (1.f - a2v); }
    }
    __syncthreads();
    if (tid == 0){
      float dd2 = 0.f, so2 = 0.f, sB2n = 0.f;
      for (int j = 0; j < CW; j++){
        float ov = o2l[j];
        dd2 += d2l[j]*ov; so2 += ov*ov;
        float B = b2l[j] - LR*ov; sB2n += B*B;
      }
      unsafeAtomicAdd(&AC[(p*16 + bank)*32 + 3], dd2);
      unsafeAtomicAdd(&AC[(p*16 + bank)*32 + 4], so2);
      unsafeAtomicAdd(&AC[(p*16 + bank)*32 + 5], sB2n);
    }
    // o1 banked partial over owned columns (prefetched s2 row)
    {
      float q0 = s2v0*o2l[0] + s2v1*o2l[1] + s2v2*o2l[2] + s2v3*o2l[3]
               + s2v4*o2l[4] + s2v5*o2l[5] + s2v6*o2l[6] + s2v7*o2l[7];
      unsafeAtomicAdd(&O1R[(p*NBANK + obank)*HID + tid], q0);
    }
    // ---- Q-arrive: block-wide drain, then bump padded counter ----
    asm volatile("s_waitcnt vmcnt(0) lgkmcnt(0)" ::: "memory");
    __syncthreads();
    if (tid == 0) iadd(&QCNT[CSTR*bank]);

    // ---- pre-Q window: Q-independent next-step work overlaps the hop ----
    {
      // cold hoists for t+1
      nxp = NX[t];                                   // NX[(t+1)-1]
      sdt = SD[(t + 1 < NSTEP) ? t + 1 : 0];
      tv_pf = (t + 1 < NSTEP && tid < OUTD) ? tgt[(size_t)(t+1)*OUTD + tid] : 0.f;
      // x row t+2 for shadow(t+1)
      xnv_pre = xdat[(size_t)(t + 2 < NSTEP ? t + 2 : NSTEP - 1)*INDIM + tid];
      // stage-2 trio for t+1 (inputs d3c/b3s/p3r all final in Phase B(t))
      if (tid < 64){
        float d3v = d3c[tid];
        float v4 = d3v*d3v;
        float B3 = b3s[tid] - LR*d3v; float v5 = B3*B3;
        float v6 = d3v * p3r[tid];
        v4 = wredf(v4); v5 = wredf(v5); v6 = wredf(v6);
        if (tid == 0){ ascr[244]=v4; ascr[245]=v5; ascr[246]=v6; }
      }
    }

    // ---- Q-wait ----
    {
      const int qtgt = (NWG/16)*(t+1);
      if (tid < 16){
        while (rload(&QCNT[CSTR*tid]) < qtgt) __builtin_amdgcn_s_sleep(1);
      }
      __syncthreads();
      asm volatile("" ::: "memory");
    }
  }
}

extern "C" void kernel_launch(void* const* d_in, const int* in_sizes, int n_in,
                              void* d_out, int out_size, void* d_ws, size_t ws_size,
                              hipStream_t stream){
  const float* x  = (const float*)d_in[0];
  const float* tg = (const float*)d_in[1];
  const float* w1 = (const float*)d_in[2];
  const float* b1 = (const float*)d_in[3];
  const float* w2 = (const float*)d_in[4];
  const float* b2 = (const float*)d_in[5];
  const float* w3 = (const float*)d_in[6];
  const float* b3 = (const float*)d_in[7];
  float* out = (float*)d_out;
  float* wsf = (float*)d_ws;
  hipLaunchKernelGGL(bp_init,  dim3(NSTEP), dim3(64),  0, stream, x, wsf);
  hipLaunchKernelGGL(bp_train, dim3(NWG),   dim3(TPB), 0, stream,
                     x, tg, w1, b1, w2, b2, w3, b3, out, wsf);
}

// Round 12
// 164515.906 us; speedup vs baseline: 1.1921x; 1.0806x over previous
//
#include <hip/hip_runtime.h>
#include <math.h>

// ---------------------------------------------------------------------------
// Persistent-kernel trainer for the 16384-step sequential MLP scan.
// R21: R20 (177.8k us) + three chain/barrier shavings, sync protocol intact:
//  1) bar#5 deleted: m2/a2sq AC adds moved tid64 -> tid8 (wave0); a2c
//     producers/consumers all wave0 -> program-order, no barrier. ascr
//     disjointness audited ([0..47] reads vs shadow's [96..239] writes).
//  2) sa1 (v3=sum a1c^2) wredf moved to pre-Q window (input = stage-3's own
//     register output); stage2 now 3 wredf chains; partials in ascr[48..63]
//     (stage2 no longer writes there; survives to t+1 reduce; prologue seeds).
//  3) Phase-B reorder: P3's 8 MALL loads issue into temps FIRST (zeroing/
//     U-store/s2-prefetch run under their latency); q0 O1R add before tid0
//     scalar AC adds.
// Base: 128WG x CW=8, s1a/s1b split, NBANK=8, P3B=8, AC 128B-padded,
// 2 hops/step (structurally irreducible: P3->o2l->q0->O1R->of0 chain).
// ---------------------------------------------------------------------------

#define NSTEP 16384
#define INDIM 1024
#define HID   1024
#define OUTD  64
#define LR    0.01f
#define EPSN  1e-8f

#define NWG   128
#define TPB   1024
#define CW    8
#define NBANK 8      // O1R banks
#define P3B   8      // P3 banks
#define CSTR  32     // counter stride in ints (128 B)

// workspace layout (float/int indices)
#define OFF_ARRIVE   0                         // 256 ints (init barrier)
#define OFF_RELEASE  512                       // 1 int
#define OFF_PCNT     1024                      // 16 counters, stride 32 ints
#define OFF_QCNT     2048                      // 16 counters, stride 32 ints
#define OFF_U        4096                      // HID floats
#define OFF_O1R      (OFF_U + HID)             // 2*NBANK*HID
#define OFF_P3       (OFF_O1R + 2*NBANK*HID)   // 2*P3B*OUTD
#define OFF_ACC      (OFF_P3 + 2*P3B*OUTD)     // 2*16*32 (banks padded to 128B)
#define OFF_SDOT     (OFF_ACC + 2*16*32)       // NSTEP
#define OFF_NORMX    (OFF_SDOT + NSTEP)        // NSTEP

// ACC slots: 0 m1, 1 m2, 2 m3, 3 dot_d2o2, 4 sum_o2sq, 5 sum_B2sq, 6 sum_a2sq

__device__ __forceinline__ float dload(const float* p){
  return __hip_atomic_load(p, __ATOMIC_RELAXED, __HIP_MEMORY_SCOPE_AGENT);
}
__device__ __forceinline__ void dstore(float* p, float v){
  __hip_atomic_store(p, v, __ATOMIC_RELAXED, __HIP_MEMORY_SCOPE_AGENT);
}
__device__ __forceinline__ int rload(const int* p){
  return __hip_atomic_load(p, __ATOMIC_RELAXED, __HIP_MEMORY_SCOPE_AGENT);
}
__device__ __forceinline__ void rstore(int* p, int v){
  __hip_atomic_store(p, v, __ATOMIC_RELAXED, __HIP_MEMORY_SCOPE_AGENT);
}
__device__ __forceinline__ void iadd(int* p){
  __hip_atomic_fetch_add(p, 1, __ATOMIC_RELAXED, __HIP_MEMORY_SCOPE_AGENT);
}
__device__ __forceinline__ float wredf(float v){
  #pragma unroll
  for (int m = 32; m; m >>= 1) v += __shfl_xor(v, m, 64);
  return v;
}
__device__ __forceinline__ float sigf(float z){ return 1.f/(1.f+__expf(-z)); }

__global__ __launch_bounds__(64) void bp_init(const float* __restrict__ x, float* wsf){
  const int t = blockIdx.x, tid = threadIdx.x;
  const float* xt = x + (size_t)t * INDIM;
  const float* xp = x + (size_t)(t > 0 ? t - 1 : 0) * INDIM;
  float sp = 0.f, nx = 0.f;
  #pragma unroll
  for (int e = 0; e < INDIM/64; e++){
    int i = tid + 64*e; float a = xt[i];
    nx += a*a; sp += a*xp[i];
  }
  sp = wredf(sp); nx = wredf(nx);
  if (tid == 0){ wsf[OFF_SDOT + t] = (t > 0) ? sp : 0.f; wsf[OFF_NORMX + t] = nx; }
  if (blockIdx.x == 0){
    int* wsi = (int*)wsf;
    for (int i = tid; i < 256; i += 64) wsi[OFF_ARRIVE + i] = 0;
    if (tid == 0) wsi[OFF_RELEASE] = 0;
    if (tid < 16){ wsi[OFF_PCNT + CSTR*tid] = 0; wsi[OFF_QCNT + CSTR*tid] = 0; }
    for (int i = tid; i < 2*NBANK*HID; i += 64) wsf[OFF_O1R + i] = 0.f;
    for (int i = tid; i < 2*P3B*OUTD;  i += 64) wsf[OFF_P3 + i]  = 0.f;
    for (int i = tid; i < 2*16*32;     i += 64) wsf[OFF_ACC + i] = 0.f;
    __syncthreads();
    if (tid == 0){
      float* acc1 = wsf + OFF_ACC + 16*32;   // parity-1, bank-0
      acc1[0] = 1.f; acc1[1] = 1.f; acc1[2] = 1.f; acc1[5] = 1.f;
    }
  }
}

__global__ __launch_bounds__(TPB) void bp_train(
    const float* __restrict__ xdat, const float* __restrict__ tgt,
    const float* __restrict__ w1g, const float* __restrict__ b1g,
    const float* __restrict__ w2g, const float* __restrict__ b2g,
    const float* __restrict__ w3g, const float* __restrict__ b3g,
    float* __restrict__ out, float* wsf)
{
  alignas(16) __shared__ float s1a[HID*4];    // w1 cols [wg*CW, wg*CW+4)
  alignas(16) __shared__ float s1b[HID*4];    // w1 cols [wg*CW+4, wg*CW+8)
  alignas(16) __shared__ float s2[CW*HID];    // w2 col-major: [j][i], 32KB
  __shared__ float s3[CW*OUTD];               // w3 rows (8x64)
  alignas(16) __shared__ float a1b[2][HID];
  __shared__ float d1s[HID];
  __shared__ float b1s[HID];
  __shared__ float o1f[HID];
  __shared__ float d3b[2][OUTD];
  __shared__ float p3r[OUTD];
  __shared__ float b3s[OUTD];
  __shared__ float o2l[CW], d2l[CW], b2l[CW];
  __shared__ float a2b[2][CW];
  __shared__ float ascr[256];

  const int tid = threadIdx.x;
  const int wg  = blockIdx.x;
  int*   arrive  = (int*)wsf + OFF_ARRIVE;
  int*   release = (int*)wsf + OFF_RELEASE;
  int*   PCNT    = (int*)wsf + OFF_PCNT;
  int*   QCNT    = (int*)wsf + OFF_QCNT;
  float* U   = wsf + OFF_U;
  float* O1R = wsf + OFF_O1R;
  float* P3  = wsf + OFF_P3;
  float* AC  = wsf + OFF_ACC;
  float* SD  = wsf + OFF_SDOT;
  float* NX  = wsf + OFF_NORMX;
  const int bank  = wg & 15;            // AC / counter bank (8 WGs each)
  const int obank = wg & (NBANK-1);     // O1R bank (16 WGs each)
  const int bank3 = wg & (P3B-1);       // P3 bank (16 WGs each)
  const int wid   = tid >> 6;

  // ---- load owned slices + replicas, zero state ----
  {
    const float4 wa = *reinterpret_cast<const float4*>(&w1g[(size_t)tid*HID + wg*CW]);
    const float4 wb = *reinterpret_cast<const float4*>(&w1g[(size_t)tid*HID + wg*CW + 4]);
    *reinterpret_cast<float4*>(&s1a[4*tid]) = wa;
    *reinterpret_cast<float4*>(&s1b[4*tid]) = wb;
  }
  for (int v = tid; v < CW*HID; v += TPB){
    int j = v & (CW-1); int i = v >> 3;
    s2[j*HID + i] = w2g[(size_t)i*HID + wg*CW + j];
  }
  if (tid < CW*OUTD){
    int i = tid >> 6; int k = tid & 63;
    s3[tid] = w3g[(size_t)(wg*CW + i)*OUTD + k];
  }
  b1s[tid] = b1g[tid]; d1s[tid] = 0.f; o1f[tid] = 0.f; a1b[1][tid] = 0.f;
  if (tid < OUTD){ b3s[tid] = b3g[tid]; d3b[1][tid] = 0.f; p3r[tid] = 0.f; }
  if (tid < CW){
    b2l[tid] = b2g[wg*CW + tid];
    o2l[tid] = 0.f; d2l[tid] = 0.f; a2b[0][tid] = 0.f; a2b[1][tid] = 0.f;
  }
  __syncthreads();

  // x-row register pipeline: xr{0,1} hold rows of x; both start at row 0
  float xr0, xr1;
  // loop-carried prefetch registers (updated in the pre-Q window)
  float nxp, sdt, tv_pf, xnv_pre;

  // ---- publish u for step 0 ----
  {
    float xv = xdat[tid];
    xr0 = xv; xr1 = xv;
    float4 wa = *reinterpret_cast<const float4*>(&s1a[4*tid]);
    float4 wb = *reinterpret_cast<const float4*>(&s1b[4*tid]);
    float u_[CW];
    u_[0] = wredf(xv*wa.x); u_[1] = wredf(xv*wa.y);
    u_[2] = wredf(xv*wa.z); u_[3] = wredf(xv*wa.w);
    u_[4] = wredf(xv*wb.x); u_[5] = wredf(xv*wb.y);
    u_[6] = wredf(xv*wb.z); u_[7] = wredf(xv*wb.w);
    if ((tid & 63) == 0){
      #pragma unroll
      for (int c = 0; c < CW; c++) ascr[96 + wid*CW + c] = u_[c];
    }
    __syncthreads();
    if (tid < CW){
      float s = 0.f;
      #pragma unroll
      for (int w2_ = 0; w2_ < 16; w2_++) s += ascr[96 + w2_*CW + tid];
      dstore(&U[wg*CW + tid], s);
    }
  }
  // ---- prologue prefetch for t=0: trio (244..246) + sa1 partials (48..63) ----
  {
    nxp = NX[0]; sdt = SD[0];
    tv_pf = (tid < OUTD) ? tgt[tid] : 0.f;
    xnv_pre = xdat[(size_t)1*INDIM + tid];         // row 1 for shadow(0)
    if ((tid & 63) == 0) ascr[48 + wid] = 0.f;     // a1b[1] == 0 -> partials 0
    if (tid < 64){
      float d3v = d3b[1][tid];                      // zeros at init
      float v4 = d3v*d3v;
      float B3 = b3s[tid] - LR*d3v; float v5 = B3*B3;
      float v6 = d3v * p3r[tid];
      v4 = wredf(v4); v5 = wredf(v5); v6 = wredf(v6);
      if (tid == 0){ ascr[244]=v4; ascr[245]=v5; ascr[246]=v6; }
    }
  }
  // initial full funnel barrier (once)
  {
    asm volatile("s_waitcnt vmcnt(0) lgkmcnt(0)" ::: "memory");
    __syncthreads();
    if (tid == 0) rstore(&arrive[wg], 1);
    if (wg == 0){
      if (tid < NWG){ while (rload(&arrive[tid]) < 1) __builtin_amdgcn_s_sleep(1); }
      __syncthreads();
      if (tid == 0) rstore(release, 1);
    }
    if (tid == 0){ while (rload(release) < 1) __builtin_amdgcn_s_sleep(1); }
    __syncthreads();
    asm volatile("" ::: "memory");
  }

  for (int t = 0; t <= NSTEP; t++){
    const int p = t & 1, qq = p ^ 1;
    float* a1c = a1b[p];  float* a1p = a1b[qq];
    float* a2c = a2b[p];  float* a2p = a2b[qq];
    float* d3c = d3b[p];  float* d3p = d3b[qq];
    float a1cv = 0.f;     // stage-3 output kept for pre-Q sa1 partial

    // ================= Phase A =================
    // O1R + U first: they feed of0, the first consumer on the critical path
    float u0 = dload(&U[tid]);
    float r0 = 0.f;
    #pragma unroll
    for (int b = 0; b < NBANK; b++)
      r0 += dload(&O1R[(qq*NBANK + b)*HID + tid]);
    // AC staging: consumed after stage 2 (latency hidden under wredf chains)
    if (tid < 112){
      int s = tid >> 4, b = tid & 15;
      ascr[128 + s*16 + b] = dload(&AC[(qq*16 + b)*32 + s]);
    }

    float a1p0 = a1p[tid];
    float of0 = r0 * a1p0 * (1.f - a1p0);
    o1f[tid] = of0;

    // stage 2: per-wave partials (3 chains; sa1 done pre-Q, trio done pre-Q)
    {
      float v0 = d1s[tid]*of0;
      float v1 = of0*of0;
      float Ba = b1s[tid] - LR*of0;
      float v2 = Ba*Ba;
      v0 = wredf(v0); v1 = wredf(v1); v2 = wredf(v2);
      if ((tid & 63) == 0){
        ascr[0*16+wid]=v0; ascr[1*16+wid]=v1; ascr[2*16+wid]=v2;
      }
    }
    __syncthreads();
    if (tid < 64){
      if (tid < 4){
        float s = 0.f;
        #pragma unroll
        for (int w = 0; w < 16; w++) s += ascr[tid*16 + w];
        ascr[240 + tid] = s;
      } else if (tid >= 8 && tid < 15){
        int s_ = tid - 8;
        float s = 0.f;
        #pragma unroll
        for (int b = 0; b < 16; b++) s += ascr[128 + s_*16 + b];
        ascr[248 + s_] = s;
      }
    }
    __syncthreads();
    float dd  = ascr[240], so  = ascr[241], sb  = ascr[242], sa1 = ascr[243];
    float sd3 = ascr[244], sb3 = ascr[245], dp3 = ascr[246];
    float m1p = ascr[248], m2p = ascr[249], m3p = ascr[250], dq  = ascr[251];
    float soq = ascr[252], sB2 = ascr[253], sa2 = ascr[254];

    float n1  = fmaxf(sqrtf(fmaxf(m1p - 2.f*LR*dd  + LR*LR*nxp*so,  0.f)), EPSN);
    float nb1 = fmaxf(sqrtf(sb),  EPSN);
    float n2  = fmaxf(sqrtf(fmaxf(m2p - 2.f*LR*dq  + LR*LR*sa1*soq, 0.f)), EPSN);
    float nb2 = fmaxf(sqrtf(sB2), EPSN);
    float n3  = fmaxf(sqrtf(fmaxf(m3p - 2.f*LR*dp3 + LR*LR*sa2*sd3, 0.f)), EPSN);
    float nb3 = fmaxf(sqrtf(sb3), EPSN);
    float rn1 = 1.f/n1, rnb1 = 1.f/nb1, rn2 = 1.f/n2, rnb2 = 1.f/nb2;
    float rn3 = 1.f/n3, rnb3 = 1.f/nb3;

    // stage 3
    {
      float B0 = (b1s[tid] - LR*of0)*rnb1; b1s[tid] = B0;
      float dn0 = (u0 - LR*of0*sdt)*rn1;   d1s[tid] = dn0;
      a1cv = sigf(dn0 + B0);
      a1c[tid] = a1cv;
    }
    __syncthreads();

    // stage 4: fused W2 update + matvec (cols j and j+4 per thread)
    {
      int j = tid >> 8, l = tid & 255;
      float coefA = LR * o2l[j];
      float coefB = LR * o2l[j+4];
      float4 wa = *reinterpret_cast<float4*>(&s2[j*HID + 4*l]);
      float4 wb = *reinterpret_cast<float4*>(&s2[(j+4)*HID + 4*l]);
      float4 ap = *reinterpret_cast<const float4*>(&a1p[4*l]);
      float4 ac = *reinterpret_cast<const float4*>(&a1c[4*l]);
      wa.x = (wa.x - coefA*ap.x)*rn2;  wa.y = (wa.y - coefA*ap.y)*rn2;
      wa.z = (wa.z - coefA*ap.z)*rn2;  wa.w = (wa.w - coefA*ap.w)*rn2;
      wb.x = (wb.x - coefB*ap.x)*rn2;  wb.y = (wb.y - coefB*ap.y)*rn2;
      wb.z = (wb.z - coefB*ap.z)*rn2;  wb.w = (wb.w - coefB*ap.w)*rn2;
      *reinterpret_cast<float4*>(&s2[j*HID + 4*l])     = wa;
      *reinterpret_cast<float4*>(&s2[(j+4)*HID + 4*l]) = wb;
      float accA = ac.x*wa.x + ac.y*wa.y + ac.z*wa.z + ac.w*wa.w;
      float accB = ac.x*wb.x + ac.y*wb.y + ac.z*wb.z + ac.w*wb.w;
      float ms   = wa.x*wa.x + wa.y*wa.y + wa.z*wa.z + wa.w*wa.w
                 + wb.x*wb.x + wb.y*wb.y + wb.z*wb.z + wb.w*wb.w;
      accA = wredf(accA); accB = wredf(accB); ms = wredf(ms);
      if ((tid & 63) == 0){ ascr[wid] = accA; ascr[32 + wid] = accB; ascr[16 + wid] = ms; }
    }
    __syncthreads();
    if (tid < CW){
      float d2;
      if (tid < 4)
        d2 = ascr[4*tid] + ascr[4*tid+1] + ascr[4*tid+2] + ascr[4*tid+3];
      else {
        int b = 32 + 4*(tid-4);
        d2 = ascr[b] + ascr[b+1] + ascr[b+2] + ascr[b+3];
      }
      d2l[tid] = d2;
      float b2n = (b2l[tid] - LR*o2l[tid])*rnb2;
      b2l[tid] = b2n;
      a2c[tid] = sigf(d2 + b2n);
    }
    // wave0 program-order: tid<8 wrote a2c; tid==8 reads it (no barrier).
    // m2 reads ascr[16..31] (covered by the stage-4 barrier above).
    if (tid == 8){
      float m2 = 0.f;
      #pragma unroll
      for (int w = 0; w < 16; w++) m2 += ascr[16 + w];
      unsafeAtomicAdd(&AC[(p*16 + bank)*32 + 1], m2);
      float s = 0.f;
      for (int j = 0; j < CW; j++){ float a = a2c[j]; s += a*a; }
      unsafeAtomicAdd(&AC[(p*16 + bank)*32 + 6], s);
    }

    // stage 5: fused W3 update + P3 publish (wave0 only; a2c intra-wave)
    if (tid < OUTD){
      int k = tid;
      float d3k = d3p[k];
      float contrib = 0.f, m3s = 0.f;
      #pragma unroll
      for (int i = 0; i < CW; i++){
        float w = s3[i*OUTD + k];
        w = (w - LR*a2p[i]*d3k)*rn3;
        s3[i*OUTD + k] = w;
        contrib += a2c[i]*w;
        m3s += w*w;
      }
      unsafeAtomicAdd(&P3[(p*P3B + bank3)*OUTD + k], contrib);
      m3s = wredf(m3s);
      if (k == 0) unsafeAtomicAdd(&AC[(p*16 + bank)*32 + 2], m3s);
      b3s[k] = (b3s[k] - LR*d3k)*rnb3;
    }

    // ===== epilogue =====
    if (t == NSTEP){
      __syncthreads();
      const float* xl = xdat + (size_t)(NSTEP - 1)*INDIM;
      float xv = xl[tid];
      float c0 = LR*o1f[wg*CW+0], c1 = LR*o1f[wg*CW+1];
      float c2 = LR*o1f[wg*CW+2], c3 = LR*o1f[wg*CW+3];
      float c4 = LR*o1f[wg*CW+4], c5 = LR*o1f[wg*CW+5];
      float c6 = LR*o1f[wg*CW+6], c7 = LR*o1f[wg*CW+7];
      float4 wa = *reinterpret_cast<const float4*>(&s1a[4*tid]);
      float4 wb = *reinterpret_cast<const float4*>(&s1b[4*tid]);
      float4 ovA, ovB;
      ovA.x = (wa.x - c0*xv)*rn1; ovA.y = (wa.y - c1*xv)*rn1;
      ovA.z = (wa.z - c2*xv)*rn1; ovA.w = (wa.w - c3*xv)*rn1;
      ovB.x = (wb.x - c4*xv)*rn1; ovB.y = (wb.y - c5*xv)*rn1;
      ovB.z = (wb.z - c6*xv)*rn1; ovB.w = (wb.w - c7*xv)*rn1;
      *reinterpret_cast<float4*>(&out[(size_t)tid*HID + wg*CW])     = ovA;
      *reinterpret_cast<float4*>(&out[(size_t)tid*HID + wg*CW + 4]) = ovB;
      float4 o2a, o2b;
      o2a.x = s2[0*HID+tid]; o2a.y = s2[1*HID+tid];
      o2a.z = s2[2*HID+tid]; o2a.w = s2[3*HID+tid];
      o2b.x = s2[4*HID+tid]; o2b.y = s2[5*HID+tid];
      o2b.z = s2[6*HID+tid]; o2b.w = s2[7*HID+tid];
      *reinterpret_cast<float4*>(&out[(size_t)HID*HID + (size_t)tid*HID + wg*CW])     = o2a;
      *reinterpret_cast<float4*>(&out[(size_t)HID*HID + (size_t)tid*HID + wg*CW + 4]) = o2b;
      if (tid < OUTD){
        #pragma unroll
        for (int i = 0; i < CW; i++)
          out[(size_t)2*HID*HID + (size_t)(wg*CW + i)*OUTD + tid] = s3[i*OUTD + tid];
      }
      break;
    }

    // ---- P-arrive: all P-side publishes are wave0's atomics ----
    if (wid == 0){
      asm volatile("s_waitcnt vmcnt(0) lgkmcnt(0)" ::: "memory");
      if (tid == 0) iadd(&PCNT[CSTR*bank]);
    }

    // ---- shadow (WG-local): fused W1 update + u_{t+1} partials + m1 ----
    float u_pub = 0.f;
    {
      float xpv = (t & 1) ? xr0 : xr1;   // row t-1, loaded 2 steps ago
      float xnv = xnv_pre;               // row t+1, loaded in pre-Q window
      if (t & 1) xr0 = xnv; else xr1 = xnv;
      float c0 = LR*o1f[wg*CW+0], c1 = LR*o1f[wg*CW+1];
      float c2 = LR*o1f[wg*CW+2], c3 = LR*o1f[wg*CW+3];
      float c4 = LR*o1f[wg*CW+4], c5 = LR*o1f[wg*CW+5];
      float c6 = LR*o1f[wg*CW+6], c7 = LR*o1f[wg*CW+7];
      float4 wa = *reinterpret_cast<float4*>(&s1a[4*tid]);
      float4 wb = *reinterpret_cast<float4*>(&s1b[4*tid]);
      wa.x = (wa.x - c0*xpv)*rn1; wa.y = (wa.y - c1*xpv)*rn1;
      wa.z = (wa.z - c2*xpv)*rn1; wa.w = (wa.w - c3*xpv)*rn1;
      wb.x = (wb.x - c4*xpv)*rn1; wb.y = (wb.y - c5*xpv)*rn1;
      wb.z = (wb.z - c6*xpv)*rn1; wb.w = (wb.w - c7*xpv)*rn1;
      *reinterpret_cast<float4*>(&s1a[4*tid]) = wa;
      *reinterpret_cast<float4*>(&s1b[4*tid]) = wb;
      float m1s = wa.x*wa.x + wa.y*wa.y + wa.z*wa.z + wa.w*wa.w
                + wb.x*wb.x + wb.y*wb.y + wb.z*wb.z + wb.w*wb.w;
      float u_[CW];
      u_[0] = wredf(xnv*wa.x); u_[1] = wredf(xnv*wa.y);
      u_[2] = wredf(xnv*wa.z); u_[3] = wredf(xnv*wa.w);
      u_[4] = wredf(xnv*wb.x); u_[5] = wredf(xnv*wb.y);
      u_[6] = wredf(xnv*wb.z); u_[7] = wredf(xnv*wb.w);
      m1s = wredf(m1s);
      if ((tid & 63) == 0){
        #pragma unroll
        for (int c = 0; c < CW; c++) ascr[96 + wid*CW + c] = u_[c];
        ascr[224 + wid] = m1s;
      }
      __syncthreads();
      if (tid < CW){
        float s = 0.f;
        #pragma unroll
        for (int w2_ = 0; w2_ < 16; w2_++) s += ascr[96 + w2_*CW + tid];
        u_pub = s;
      }
      if (tid == 0){
        float m1 = 0.f;
        #pragma unroll
        for (int w2_ = 0; w2_ < 16; w2_++) m1 += ascr[224 + w2_];
        unsafeAtomicAdd(&AC[(p*16 + bank)*32 + 0], m1);
      }
    }

    // ---- P-wait: poll 16 padded producer counters (one line each) ----
    {
      const int ptgt = (NWG/16)*(t+1);
      if (tid < 16){
        while (rload(&PCNT[CSTR*tid]) < ptgt) __builtin_amdgcn_s_sleep(1);
      }
      __syncthreads();
      asm volatile("" ::: "memory");
    }

    // ================= Phase B =================
    // P3 loads FIRST (8 MALL reads in flight), then independent work
    float p0v=0.f,p1v=0.f,p2v=0.f,p3v=0.f,p4v=0.f,p5v=0.f,p6v=0.f,p7v=0.f;
    if (tid < OUTD){
      p0v = dload(&P3[(p*P3B + 0)*OUTD + tid]);
      p1v = dload(&P3[(p*P3B + 1)*OUTD + tid]);
      p2v = dload(&P3[(p*P3B + 2)*OUTD + tid]);
      p3v = dload(&P3[(p*P3B + 3)*OUTD + tid]);
      p4v = dload(&P3[(p*P3B + 4)*OUTD + tid]);
      p5v = dload(&P3[(p*P3B + 5)*OUTD + tid]);
      p6v = dload(&P3[(p*P3B + 6)*OUTD + tid]);
      p7v = dload(&P3[(p*P3B + 7)*OUTD + tid]);
    }
    // early zeroing of next-parity accumulators (safe: P-wait proves all WGs
    // consumed their Phase-A qq reads); acks overlap Phase B compute
    if (wg < NBANK) dstore(&O1R[(qq*NBANK + wg)*HID + tid], 0.f);
    if (wg < P3B && tid < OUTD) dstore(&P3[(qq*P3B + wg)*OUTD + tid], 0.f);
    if (wg < 16  && tid < 8)    dstore(&AC[(qq*16 + wg)*32 + tid], 0.f);
    if (tid < CW) dstore(&U[wg*CW + tid], u_pub);   // safe: all WGs past A stage1
    // prefetch s2 row (stable since stage 4) for the o1 partial
    float s2v0 = s2[0*HID+tid], s2v1 = s2[1*HID+tid];
    float s2v2 = s2[2*HID+tid], s2v3 = s2[3*HID+tid];
    float s2v4 = s2[4*HID+tid], s2v5 = s2[5*HID+tid];
    float s2v6 = s2[6*HID+tid], s2v7 = s2[7*HID+tid];

    if (tid < OUTD){
      float s = ((p0v + p1v) + (p2v + p3v)) + ((p4v + p5v) + (p6v + p7v));
      p3r[tid] = s;
      float a3 = sigf(s + b3s[tid]);
      float e3 = __expf(-a3);
      float es = wredf(e3);
      float net = e3 / es;
      d3c[tid] = (tv_pf - net) * a3 * (1.f - a3);
    }
    __syncthreads();
    if (tid < CW*OUTD){
      int i = tid >> 6, k = tid & 63;
      float v = wredf(s3[i*OUTD + k] * d3c[k]);
      if (k == 0){ float a2v = a2c[i]; o2l[i] = v * a2v * (1.f - a2v); }
    }
    __syncthreads();
    // o1 banked partial first (wave-wide RMW in flight), then scalar AC adds
    {
      float q0 = s2v0*o2l[0] + s2v1*o2l[1] + s2v2*o2l[2] + s2v3*o2l[3]
               + s2v4*o2l[4] + s2v5*o2l[5] + s2v6*o2l[6] + s2v7*o2l[7];
      unsafeAtomicAdd(&O1R[(p*NBANK + obank)*HID + tid], q0);
    }
    if (tid == 0){
      float dd2 = 0.f, so2 = 0.f, sB2n = 0.f;
      for (int j = 0; j < CW; j++){
        float ov = o2l[j];
        dd2 += d2l[j]*ov; so2 += ov*ov;
        float B = b2l[j] - LR*ov; sB2n += B*B;
      }
      unsafeAtomicAdd(&AC[(p*16 + bank)*32 + 3], dd2);
      unsafeAtomicAdd(&AC[(p*16 + bank)*32 + 4], so2);
      unsafeAtomicAdd(&AC[(p*16 + bank)*32 + 5], sB2n);
    }
    // ---- Q-arrive: block-wide drain, then bump padded counter ----
    asm volatile("s_waitcnt vmcnt(0) lgkmcnt(0)" ::: "memory");
    __syncthreads();
    if (tid == 0) iadd(&QCNT[CSTR*bank]);

    // ---- pre-Q window: Q-independent next-step work overlaps the hop ----
    {
      // cold hoists for t+1
      nxp = NX[t];                                   // NX[(t+1)-1]
      sdt = SD[(t + 1 < NSTEP) ? t + 1 : 0];
      tv_pf = (t + 1 < NSTEP && tid < OUTD) ? tgt[(size_t)(t+1)*OUTD + tid] : 0.f;
      // x row t+2 for shadow(t+1)
      xnv_pre = xdat[(size_t)(t + 2 < NSTEP ? t + 2 : NSTEP - 1)*INDIM + tid];
      // sa1 partials for t+1 (input: this step's stage-3 register output)
      float v3 = wredf(a1cv*a1cv);
      if ((tid & 63) == 0) ascr[48 + wid] = v3;
      // stage-2 trio for t+1 (inputs d3c/b3s/p3r all final in Phase B(t))
      if (tid < 64){
        float d3v = d3c[tid];
        float v4 = d3v*d3v;
        float B3 = b3s[tid] - LR*d3v; float v5 = B3*B3;
        float v6 = d3v * p3r[tid];
        v4 = wredf(v4); v5 = wredf(v5); v6 = wredf(v6);
        if (tid == 0){ ascr[244]=v4; ascr[245]=v5; ascr[246]=v6; }
      }
    }

    // ---- Q-wait ----
    {
      const int qtgt = (NWG/16)*(t+1);
      if (tid < 16){
        while (rload(&QCNT[CSTR*tid]) < qtgt) __builtin_amdgcn_s_sleep(1);
      }
      __syncthreads();
      asm volatile("" ::: "memory");
    }
  }
}

extern "C" void kernel_launch(void* const* d_in, const int* in_sizes, int n_in,
                              void* d_out, int out_size, void* d_ws, size_t ws_size,
                              hipStream_t stream){
  const float* x  = (const float*)d_in[0];
  const float* tg = (const float*)d_in[1];
  const float* w1 = (const float*)d_in[2];
  const float* b1 = (const float*)d_in[3];
  const float* w2 = (const float*)d_in[4];
  const float* b2 = (const float*)d_in[5];
  const float* w3 = (const float*)d_in[6];
  const float* b3 = (const float*)d_in[7];
  float* out = (float*)d_out;
  float* wsf = (float*)d_ws;
  hipLaunchKernelGGL(bp_init,  dim3(NSTEP), dim3(64),  0, stream, x, wsf);
  hipLaunchKernelGGL(bp_train, dim3(NWG),   dim3(TPB), 0, stream,
                     x, tg, w1, b1, w2, b2, w3, b3, out, wsf);
}